// Round 8
// baseline (180.753 us; speedup 1.0000x reference)
//
#include <hip/hip_runtime.h>
#include <hip/hip_cooperative_groups.h>
#include <math.h>

namespace cg = cooperative_groups;

// Problem constants (B=2, T=2048, D=1024, H=16, HD=64, C=16)
#define B_    2
#define T_    2048
#define D_    1024
#define H_    16
#define HD_   64
#define C_    16
#define SCALE_ 0.125f      // HEAD_DIM^-0.5
#define L_    128          // time-chunk length
#define NC_   16           // T_/L_
#define QKP_  512          // qkcv row pitch: [qc(256) | kc(256)]

typedef __attribute__((ext_vector_type(8))) short short8;
typedef __attribute__((ext_vector_type(4))) float f32x4;

__device__ inline float b2f(uint32_t u16) {
    return __uint_as_float(u16 << 16);
}
__device__ inline ushort f2b(float f) {   // RNE
    uint32_t u = __float_as_uint(f);
    return (ushort)((u + 0x7FFFu + ((u >> 16) & 1u)) >> 16);
}
__device__ inline uint32_t pack2(float a, float b) {
    return (uint32_t)f2b(a) | ((uint32_t)f2b(b) << 16);
}
__device__ inline void unpack2(uint32_t w, float& a, float& b) {
    a = b2f(w & 0xffffu); b = __uint_as_float(w & 0xffff0000u);
}
__device__ inline void unpack8(uint4 raw, float* dst) {
    unpack2(raw.x, dst[0], dst[1]);
    unpack2(raw.y, dst[2], dst[3]);
    unpack2(raw.z, dst[4], dst[5]);
    unpack2(raw.w, dst[6], dst[7]);
}
__device__ __forceinline__ void gll16(const ushort* g, ushort* l) {
    __builtin_amdgcn_global_load_lds(
        (const __attribute__((address_space(1))) void*)g,
        (__attribute__((address_space(3))) void*)l, 16, 0, 0);
}

// ---------------------------------------------------------------------------
// Merged input prep: blockIdx ranges
//   [0,2048)    : cast x fp32 -> bf16
//   [2048,3072) : cast Wv / w_out -> bf16
//   [3072,3200) : fold fc_code into q/k slices -> WallB rows 0..511
__global__ __launch_bounds__(256)
void prep_inputs_kernel(const float* __restrict__ x, const float* __restrict__ w_qkv,
                        const float* __restrict__ w_out, const float* __restrict__ code,
                        ushort* __restrict__ xb, ushort* __restrict__ WallB,
                        ushort* __restrict__ WoB) {
    const int bid = blockIdx.x;
    if (bid < 3072) {
        const float* in;
        ushort* out;
        int i;
        if (bid < 2048) {
            in = x; out = xb;
            i = bid * 2048 + threadIdx.x * 8;
        } else {
            const int sub = bid - 2048;
            const int isW = sub >> 9;
            in = isW ? w_out : (w_qkv + (size_t)2048 * 1024);
            out = isW ? WoB : (WallB + (size_t)512 * 1024);
            i = (sub & 511) * 2048 + threadIdx.x * 8;
        }
        float4 a = *(const float4*)(in + i);
        float4 b = *(const float4*)(in + i + 4);
        uint4 o;
        o.x = pack2(a.x, a.y); o.y = pack2(a.z, a.w);
        o.z = pack2(b.x, b.y); o.w = pack2(b.z, b.w);
        *(uint4*)(out + i) = o;
    } else {
        const int sub = bid - 3072;      // 0..127
        const int isK = sub >> 6;
        const int h   = (sub >> 2) & 15;
        const int eq  = sub & 3;
        const int e   = eq * 256 + threadIdx.x;
        __shared__ __align__(16) float cs[C_][HD_];   // code[h] slice, 4 KB
        {
            float* csf = &cs[0][0];
            *(float4*)(csf + threadIdx.x * 4) =
                *(const float4*)(code + h * 1024 + threadIdx.x * 4);
        }
        __syncthreads();
        const float* wbase = w_qkv + ((size_t)(isK * D_ + h * HD_)) * D_ + e;
        float acc[C_];
        #pragma unroll
        for (int c = 0; c < C_; ++c) acc[c] = 0.f;
        #pragma unroll 4
        for (int db = 0; db < 16; ++db) {
            const float w0 = wbase[(size_t)(db * 4 + 0) * D_];
            const float w1 = wbase[(size_t)(db * 4 + 1) * D_];
            const float w2 = wbase[(size_t)(db * 4 + 2) * D_];
            const float w3 = wbase[(size_t)(db * 4 + 3) * D_];
            #pragma unroll
            for (int c = 0; c < C_; ++c) {
                float4 cv = *(const float4*)&cs[c][db * 4];
                acc[c] += w0 * cv.x; acc[c] += w1 * cv.y;
                acc[c] += w2 * cv.z; acc[c] += w3 * cv.w;
            }
        }
        ushort* outp = WallB + (size_t)(isK * 256 + h * 16) * D_ + e;
        #pragma unroll
        for (int c = 0; c < C_; ++c)
            outp[(size_t)c * D_] = f2b(acc[c] * SCALE_);
    }
}

// ---------------------------------------------------------------------------
// bf16 MFMA GEMM: C[M,N] = A[M,K] @ B[N,K]^T.
// Tile 128x64 (BM x BN), BK=64, 4 waves (wave-tile 32x64, acc 2x4).
// MODE 0: fp32 C (pitch N).
// MODE 2: gemm1 fused output: cols<512 -> qkcv bf16 (pitch 512);
//         cols>=512 are v -> written TRANSPOSED to vT[bh][d][t].
template<int MODE>
__global__ __launch_bounds__(256)
void gemm_bf16_kernel(const ushort* __restrict__ A, const ushort* __restrict__ Bw,
                      void* __restrict__ Cv, ushort* __restrict__ vTout,
                      int M, int N, int K) {
    __shared__ ushort As[2][128 * 64];   // 2 x 16 KB
    __shared__ ushort Bs[2][64 * 64];    // 2 x 8 KB
    const int tid  = threadIdx.x;
    const int wave = tid >> 6;
    const int lane = tid & 63;

    // XCD swizzle: contiguous tile chunk per XCD (bijective: nwg % 8 == 0)
    const int gx = gridDim.x;
    int f = blockIdx.y * gx + blockIdx.x;
    const int nwg = gx * gridDim.y;
    if ((nwg & 7) == 0) f = (f & 7) * (nwg >> 3) + (f >> 3);
    const int row0 = (f / gx) * 128;
    const int col0 = (f % gx) * 64;

    f32x4 acc[2][4];
    #pragma unroll
    for (int m = 0; m < 2; ++m)
        #pragma unroll
        for (int n = 0; n < 4; ++n) acc[m][n] = (f32x4){0.f, 0.f, 0.f, 0.f};

    // staging constants: linear LDS dest, pre-swizzled global source
    const int srow = lane >> 3;
    const int kA   = ((lane & 7) ^ srow) << 3;
    // fragment-read constants
    const int lane15 = lane & 15;
    const int lhi    = lane >> 4;
    const int axor   = (lane15 & 7) << 4;

    const int NT = K >> 6;

    // stage: 24 segs total (A:16, B:8), 6 per wave
    auto STAGE = [&](int buf, int kk) {
        #pragma unroll
        for (int i = 0; i < 6; ++i) {
            const int sg = wave * 6 + i;
            if (sg < 16) {
                const int r = sg * 8 + srow;
                gll16(A + (size_t)(row0 + r) * K + kk + kA, &As[buf][sg * 512]);
            } else {
                const int sb = sg - 16;
                const int r = sb * 8 + srow;
                gll16(Bw + (size_t)(col0 + r) * K + kk + kA, &Bs[buf][sb * 512]);
            }
        }
    };

    STAGE(0, 0);
    __syncthreads();

    for (int it = 0; it < NT; ++it) {
        const int cur = it & 1;
        if (it + 1 < NT) STAGE(cur ^ 1, (it + 1) << 6);
        const char* Ab = (const char*)As[cur];
        const char* Bb = (const char*)Bs[cur];
        #pragma unroll
        for (int s = 0; s < 2; ++s) {
            short8 af[2], bf[4];
            #pragma unroll
            for (int m = 0; m < 2; ++m) {
                const int r = wave * 32 + m * 16 + lane15;
                const int off = (r * 128 + s * 64 + lhi * 16) ^ axor;
                af[m] = *(const short8*)(Ab + off);
            }
            #pragma unroll
            for (int n = 0; n < 4; ++n) {
                const int r = n * 16 + lane15;
                const int off = (r * 128 + s * 64 + lhi * 16) ^ axor;
                bf[n] = *(const short8*)(Bb + off);
            }
            #pragma unroll
            for (int m = 0; m < 2; ++m)
                #pragma unroll
                for (int n = 0; n < 4; ++n)
                    acc[m][n] = __builtin_amdgcn_mfma_f32_16x16x32_bf16(
                        af[m], bf[n], acc[m][n], 0, 0, 0);
        }
        __syncthreads();   // drains prefetch (vmcnt 0) + protects buffers
    }

    // epilogue: C/D map col=lane&15, row=(lane>>4)*4+j
    #pragma unroll
    for (int m = 0; m < 2; ++m) {
        #pragma unroll
        for (int n = 0; n < 4; ++n) {
            const int row = row0 + wave * 32 + m * 16 + lhi * 4;
            const int col = col0 + n * 16 + lane15;
            if (MODE == 0) {
                float* C = (float*)Cv;
                #pragma unroll
                for (int j = 0; j < 4; ++j)
                    C[(size_t)(row + j) * N + col] = acc[m][n][j];
            } else {   // MODE 2
                if (col0 < 512) {
                    ushort* C = (ushort*)Cv;
                    #pragma unroll
                    for (int j = 0; j < 4; ++j)
                        C[(size_t)(row + j) * QKP_ + col] = f2b(acc[m][n][j]);
                } else {
                    const int dg = col - 512;
                    const int h = dg >> 6, d = dg & 63;
                    const int b = row >> 11;
                    const int t = row & 2047;
                    ushort* p = vTout + ((size_t)((b * 16 + h) * 64 + d)) * 2048 + t;
                    *(uint2*)p = make_uint2(pack2(acc[m][n][0], acc[m][n][1]),
                                            pack2(acc[m][n][2], acc[m][n][3]));
                }
            }
        }
    }
}

// ---------------------------------------------------------------------------
// COOPERATIVE merged attention kernel, 512 blocks x 512 threads, 2 blocks/CU.
// Phase A (pre grid.sync): stage ke(bf16)+keT+Vt once; waves 0-3 compute
//   kv_loc[d][c] = sum_t v[t,d]*ke[t,c] via 16 MFMAs; waves 4-7 compute
//   ke_loc[c] = sum_t ke[t,c].
// Phase B (post grid.sync): exclusive chunk-prefix (S0/e0) from other blocks'
//   phase-A output, kesum scan, softmax->qn, QK^T (causal) -> Pl, O = Qn*S0 + P*V.
// LDS: keT and kesum aliased into Pl (disjoint lifetimes). Total ~69 KB.
__global__ __launch_bounds__(512, 4)
void intra_coop_kernel(const ushort* __restrict__ qkcv, const ushort* __restrict__ vT,
                       float* __restrict__ ke_loc, float* __restrict__ kv_loc,
                       ushort* __restrict__ xob) {
    const int bid = blockIdx.x;
    const int chunk = bid & (NC_ - 1);
    const int bh = bid >> 4;
    const int b = bh >> 4, h = bh & 15;
    const int t0 = chunk * L_;
    const int tid = threadIdx.x;
    const int wave = tid >> 6, lane = tid & 63;
    const int l15 = lane & 15, lhi = lane >> 4;

    __shared__ __align__(16) ushort ke_bf[128 * 32];   // 8 KB
    __shared__ __align__(16) ushort qn_bf[128 * 32];   // 8 KB
    __shared__ __align__(16) ushort Vt_s[64 * 128];    // 16 KB
    __shared__ __align__(16) ushort Pl[128 * 128];     // 32 KB (hosts keT + kesum early)
    __shared__ __align__(16) ushort S0t[64 * 32];      // 4 KB
    __shared__ float gsum[16][16];
    __shared__ float e0s[16];

    char* keB = (char*)ke_bf;
    char* qnB = (char*)qn_bf;
    char* vtB = (char*)Vt_s;
    char* plB = (char*)Pl;
    char* s0B = (char*)S0t;
    char* keT = plB;                         // [16 c][128 t] bf16, swz ^(c<<4); phase A only
    float* kesum = (float*)(plB + 4096);     // [128 t][16 c] fp32; dead before QK writes Pl

    // ================= PHASE A =================
    // ---- stage ke = exp(kc) as bf16 (+ zero pad) and keT transpose ----
    if (tid < 256) {
        const int t = tid >> 1, c0 = (tid & 1) * 8;
        uint4 raw = *(const uint4*)(qkcv + (size_t)(b * T_ + t0 + t) * QKP_ + 256 + h * C_ + c0);
        float f[8]; unpack8(raw, f);
        float ef[8];
        #pragma unroll
        for (int j = 0; j < 8; ++j) ef[j] = __expf(f[j]);
        uint4 o;
        o.x = pack2(ef[0], ef[1]); o.y = pack2(ef[2], ef[3]);
        o.z = pack2(ef[4], ef[5]); o.w = pack2(ef[6], ef[7]);
        const int swz = ((t >> 1) & 3) << 4;
        *(uint4*)(keB + ((t * 64 + c0 * 2) ^ swz)) = o;
        *(uint4*)(keB + ((t * 64 + 32 + c0 * 2) ^ swz)) = make_uint4(0, 0, 0, 0);
        #pragma unroll
        for (int j = 0; j < 8; ++j) {
            const int c = c0 + j;
            *(ushort*)(keT + (((c << 8) + (t << 1)) ^ (c << 4))) = f2b(ef[j]);
        }
    }
    // ---- stage Vt (bf16 [d][s] swizzled) from vT global, all 512 threads ----
    {
        const int d = tid >> 3, qq = tid & 7;
        const ushort* src = vT + ((size_t)bh * 64 + d) * 2048 + t0 + qq * 16;
        const int swz = (d & 15) << 4;
        #pragma unroll
        for (int ii = 0; ii < 2; ++ii) {
            uint4 raw = *(const uint4*)(src + ii * 8);
            *(uint4*)(vtB + ((d * 256 + qq * 32 + ii * 16) ^ swz)) = raw;
        }
    }
    __syncthreads();

    // ---- waves 0-3: kv^T[d][c] via MFMA; waves 4-7: ke column partial sums ----
    if (wave < 4) {
        const int dt = wave;
        f32x4 kacc = (f32x4){0.f, 0.f, 0.f, 0.f};
        #pragma unroll
        for (int ks = 0; ks < 4; ++ks) {
            const int d = dt * 16 + l15;
            short8 av = *(const short8*)(vtB + ((d * 256 + ks * 64 + lhi * 16) ^ ((d & 15) << 4)));
            short8 bk = *(const short8*)(keT + (((l15 << 8) + ks * 64 + lhi * 16) ^ (l15 << 4)));
            kacc = __builtin_amdgcn_mfma_f32_16x16x32_bf16(av, bk, kacc, 0, 0, 0);
        }
        float* kvb = kv_loc + (size_t)bid * 1024;
        #pragma unroll
        for (int j = 0; j < 4; ++j)
            kvb[(dt * 16 + lhi * 4 + j) * 16 + l15] = kacc[j];
    } else {
        const int cc = tid & 15, g = (tid >> 4) & 15;
        float s = 0.f;
        #pragma unroll
        for (int u = 0; u < 8; ++u) {
            const int t = g * 8 + u;
            s += b2f(*(const ushort*)(keB + ((t * 64 + cc * 2) ^ (((t >> 1) & 3) << 4))));
        }
        gsum[cc][g] = s;
    }
    __syncthreads();
    if (tid < 16) {
        float s = 0.f;
        #pragma unroll
        for (int g = 0; g < 16; ++g) s += gsum[tid][g];
        ke_loc[(size_t)bid * C_ + tid] = s;
    }
    __threadfence();
    cg::this_grid().sync();

    // ================= PHASE B =================
    // ---- exclusive chunk-prefix: S0t[d][c] = sum_{ch<chunk} kv_loc[ch][d][c] ----
    if (tid < 256) {
        const int d = tid >> 2;
        const int c0 = (tid & 3) * 4;
        const float* base = kv_loc + (size_t)(bh * NC_) * 1024 + d * 16 + c0;
        float s0 = 0.f, s1 = 0.f, s2 = 0.f, s3 = 0.f;
        for (int ch = 0; ch < chunk; ++ch) {
            float4 t4 = *(const float4*)(base + ch * 1024);
            s0 += t4.x; s1 += t4.y; s2 += t4.z; s3 += t4.w;
        }
        const int swz2 = ((d >> 1) & 3) << 4;
        *(uint2*)(s0B + ((d * 64 + c0 * 2) ^ swz2)) =
            make_uint2(pack2(s0, s1), pack2(s2, s3));
        // zero-pad cols 16..31 (bytes 32..63)
        *(uint2*)(s0B + ((d * 64 + 32 + (tid & 3) * 8) ^ swz2)) = make_uint2(0, 0);
    }
    if (tid < 16) {
        float s = 0.f;
        for (int ch = 0; ch < chunk; ++ch)
            s += ke_loc[(size_t)(bh * NC_ + ch) * C_ + tid];
        e0s[tid] = s;
    }
    // ---- two-level inclusive prefix of ke over t (+ e0) -> kesum ----
    if (tid < 256) {
        const int cc = tid & 15, g = tid >> 4;
        float s = 0.f;
        #pragma unroll
        for (int u = 0; u < 8; ++u) {
            const int t = g * 8 + u;
            s += b2f(*(const ushort*)(keB + ((t * 64 + cc * 2) ^ (((t >> 1) & 3) << 4))));
        }
        gsum[cc][g] = s;
    }
    __syncthreads();
    if (tid < 16) {
        float run = e0s[tid];
        #pragma unroll
        for (int g = 0; g < 16; ++g) { float tmp = gsum[tid][g]; gsum[tid][g] = run; run += tmp; }
    }
    __syncthreads();
    if (tid < 256) {
        const int cc = tid & 15, g = tid >> 4;
        float run = gsum[cc][g];
        #pragma unroll
        for (int u = 0; u < 8; ++u) {
            const int t = g * 8 + u;
            run += b2f(*(const ushort*)(keB + ((t * 64 + cc * 2) ^ (((t >> 1) & 3) << 4))));
            kesum[t * 16 + cc] = run;
        }
    }
    __syncthreads();

    // ---- qn = softmax(qc)*scale/(kesum+eps), bf16 (+ zero pad) ----
    if (tid < 128) {
        const int t = tid;
        const ushort* qrow = qkcv + (size_t)(b * T_ + t0 + t) * QKP_ + h * C_;
        float qv[16];
        uint4 r0 = *(const uint4*)qrow, r1 = *(const uint4*)(qrow + 8);
        unpack8(r0, qv); unpack8(r1, qv + 8);
        float m = qv[0];
        #pragma unroll
        for (int c = 1; c < 16; ++c) m = fmaxf(m, qv[c]);
        float sum = 0.f;
        #pragma unroll
        for (int c = 0; c < 16; ++c) { qv[c] = __expf(qv[c] - m); sum += qv[c]; }
        const float inv = SCALE_ / sum;
        #pragma unroll
        for (int c = 0; c < 16; ++c) qv[c] = qv[c] * inv / (kesum[t * 16 + c] + 1e-9f);
        uint4 o0, o1;
        o0.x = pack2(qv[0], qv[1]);   o0.y = pack2(qv[2], qv[3]);
        o0.z = pack2(qv[4], qv[5]);   o0.w = pack2(qv[6], qv[7]);
        o1.x = pack2(qv[8], qv[9]);   o1.y = pack2(qv[10], qv[11]);
        o1.z = pack2(qv[12], qv[13]); o1.w = pack2(qv[14], qv[15]);
        const int swz = ((t >> 1) & 3) << 4;
        *(uint4*)(qnB + ((t * 64) ^ swz)) = o0;
        *(uint4*)(qnB + ((t * 64 + 16) ^ swz)) = o1;
        *(uint4*)(qnB + ((t * 64 + 32) ^ swz)) = make_uint4(0, 0, 0, 0);
        *(uint4*)(qnB + ((t * 64 + 48) ^ swz)) = make_uint4(0, 0, 0, 0);
    }
    __syncthreads();

    // ---- QK: one s-block per wave: P^T = Ke·Qn^T, mask, write Pl ----
    {
        const int sb = wave;               // 0..7
        const int s_row = sb * 16 + l15;
        short8 af = *(const short8*)(keB + ((s_row * 64 + lhi * 16) ^ (((s_row >> 1) & 3) << 4)));
        #pragma unroll
        for (int tb = 0; tb < 8; ++tb) {
            f32x4 p = (f32x4){0.f, 0.f, 0.f, 0.f};
            if (tb >= sb) {
                const int t_col = tb * 16 + l15;
                short8 bf = *(const short8*)(qnB + ((t_col * 64 + lhi * 16) ^ (((t_col >> 1) & 3) << 4)));
                p = __builtin_amdgcn_mfma_f32_16x16x32_bf16(af, bf, p, 0, 0, 0);
                if (tb == sb) {
                    #pragma unroll
                    for (int j = 0; j < 4; ++j)
                        p[j] = (lhi * 4 + j > l15) ? 0.f : p[j];
                }
            }
            const int t_g = tb * 16 + l15;
            const int sbase = sb * 16 + lhi * 4;
            const int swz = (t_g & 15) << 4;
            *(uint32_t*)(plB + ((t_g * 256 + sbase * 2) ^ swz)) = pack2(p[0], p[1]);
            *(uint32_t*)(plB + ((t_g * 256 + sbase * 2 + 4) ^ swz)) = pack2(p[2], p[3]);
        }
    }
    __syncthreads();

    // ---- O = Qn·S0 + P·V : one t-tile per wave ----
    f32x4 acc4[4];
    #pragma unroll
    for (int dt = 0; dt < 4; ++dt) acc4[dt] = (f32x4){0.f, 0.f, 0.f, 0.f};

    {
        const int t_g = wave * 16 + l15;
        short8 aq = *(const short8*)(qnB + ((t_g * 64 + lhi * 16) ^ (((t_g >> 1) & 3) << 4)));
        #pragma unroll
        for (int dt = 0; dt < 4; ++dt) {
            const int d = dt * 16 + l15;
            short8 bs = *(const short8*)(s0B + ((d * 64 + lhi * 16) ^ (((d >> 1) & 3) << 4)));
            acc4[dt] = __builtin_amdgcn_mfma_f32_16x16x32_bf16(aq, bs, acc4[dt], 0, 0, 0);
        }
        const int pswz = (t_g & 15) << 4;
        #pragma unroll
        for (int kb = 0; kb < 4; ++kb) {
            short8 ap = *(const short8*)(plB + ((t_g * 256 + kb * 64 + lhi * 16) ^ pswz));
            #pragma unroll
            for (int dt = 0; dt < 4; ++dt) {
                const int d = dt * 16 + l15;
                short8 bv = *(const short8*)(vtB + ((d * 256 + kb * 64 + lhi * 16) ^ ((d & 15) << 4)));
                acc4[dt] = __builtin_amdgcn_mfma_f32_16x16x32_bf16(ap, bv, acc4[dt], 0, 0, 0);
            }
        }
    }

    // ---- epilogue ----
    {
        const int tg0 = t0 + wave * 16 + lhi * 4;
        #pragma unroll
        for (int dt = 0; dt < 4; ++dt) {
            const int d = dt * 16 + l15;
            ushort* orow = xob + (size_t)(b * T_ + tg0) * D_ + h * HD_ + d;
            #pragma unroll
            for (int j = 0; j < 4; ++j)
                orow[(size_t)j * D_] = f2b(acc4[dt][j]);
        }
    }
}

// ---------------------------------------------------------------------------
extern "C" void kernel_launch(void* const* d_in, const int* in_sizes, int n_in,
                              void* d_out, int out_size, void* d_ws, size_t ws_size,
                              hipStream_t stream) {
    const float* x     = (const float*)d_in[0];   // (2,2048,1024)
    const float* w_qkv = (const float*)d_in[1];   // (3072,1024)
    const float* w_out = (const float*)d_in[2];   // (1024,1024)
    const float* code  = (const float*)d_in[3];   // (1,16,16,64)
    float* out = (float*)d_out;                   // (2,2048,1024)

    ushort* xb    = (ushort*)d_ws;                    // 4096*1024
    ushort* WallB = xb + (size_t)4096 * 1024;         // 1536*1024
    ushort* WoB   = WallB + (size_t)1536 * 1024;      // 1024*1024
    ushort* qkcv  = WoB + (size_t)1024 * 1024;        // 4096*512 (qc|kc)
    ushort* xob   = qkcv + (size_t)4096 * 512;        // 4096*1024
    ushort* vT    = xob + (size_t)4096 * 1024;        // 32*64*2048
    float*  ke_loc = (float*)(vT + (size_t)32 * 64 * 2048);  // 512*16
    float*  kv_loc = ke_loc + 512 * 16;               // 512*1024 ([d][c] per chunk)

    // merged casts + weight folding (one launch)
    prep_inputs_kernel<<<3200, 256, 0, stream>>>(x, w_qkv, w_out, code, xb, WallB, WoB);

    // fused qc|kc|v projection: (4096 x 1536 x 1024); qc/kc -> qkcv, v -> vT (transposed)
    gemm_bf16_kernel<2><<<dim3(24, 32), 256, 0, stream>>>(xb, WallB, qkcv, vT, 4096, 1536, 1024);

    // cooperative merged attention (phase A locals + grid sync + phase B intra)
    {
        void* kargs[] = {(void*)&qkcv, (void*)&vT, (void*)&ke_loc, (void*)&kv_loc, (void*)&xob};
        hipLaunchCooperativeKernel((const void*)intra_coop_kernel,
                                   dim3(512), dim3(512), kargs, 0, stream);
    }

    // out = xo @ w_out^T  (4096 x 1024 x 1024), fp32 out
    gemm_bf16_kernel<0><<<dim3(16, 32), 256, 0, stream>>>(xob, WoB, out, nullptr, 4096, 1024, 1024);
}

// Round 9
// 78.132 us; speedup vs baseline: 2.3134x; 2.3134x over previous
//
#include <hip/hip_runtime.h>
#include <math.h>

// Problem constants (B=2, T=2048, D=1024, H=16, HD=64, C=16)
#define B_    2
#define T_    2048
#define D_    1024
#define H_    16
#define HD_   64
#define C_    16
#define SCALE_ 0.125f      // HEAD_DIM^-0.5
#define L_    128          // time-chunk length
#define NC_   16           // T_/L_
#define QKP_  512          // qkcv row pitch: [qc(256) | kc(256)]

typedef __attribute__((ext_vector_type(8))) short short8;
typedef __attribute__((ext_vector_type(4))) float f32x4;

__device__ inline float b2f(uint32_t u16) {
    return __uint_as_float(u16 << 16);
}
__device__ inline ushort f2b(float f) {   // RNE
    uint32_t u = __float_as_uint(f);
    return (ushort)((u + 0x7FFFu + ((u >> 16) & 1u)) >> 16);
}
__device__ inline uint32_t pack2(float a, float b) {
    return (uint32_t)f2b(a) | ((uint32_t)f2b(b) << 16);
}
__device__ inline void unpack2(uint32_t w, float& a, float& b) {
    a = b2f(w & 0xffffu); b = __uint_as_float(w & 0xffff0000u);
}
__device__ inline void unpack8(uint4 raw, float* dst) {
    unpack2(raw.x, dst[0], dst[1]);
    unpack2(raw.y, dst[2], dst[3]);
    unpack2(raw.z, dst[4], dst[5]);
    unpack2(raw.w, dst[6], dst[7]);
}
__device__ __forceinline__ void gll16(const ushort* g, ushort* l) {
    __builtin_amdgcn_global_load_lds(
        (const __attribute__((address_space(1))) void*)g,
        (__attribute__((address_space(3))) void*)l, 16, 0, 0);
}

// ---------------------------------------------------------------------------
// Merged input prep: blockIdx ranges
//   [0,2048)    : cast x fp32 -> bf16
//   [2048,3072) : cast Wv / w_out -> bf16
//   [3072,3200) : fold fc_code into q/k slices -> WallB rows 0..511
__global__ __launch_bounds__(256)
void prep_inputs_kernel(const float* __restrict__ x, const float* __restrict__ w_qkv,
                        const float* __restrict__ w_out, const float* __restrict__ code,
                        ushort* __restrict__ xb, ushort* __restrict__ WallB,
                        ushort* __restrict__ WoB) {
    const int bid = blockIdx.x;
    if (bid < 3072) {
        const float* in;
        ushort* out;
        int i;
        if (bid < 2048) {
            in = x; out = xb;
            i = bid * 2048 + threadIdx.x * 8;
        } else {
            const int sub = bid - 2048;
            const int isW = sub >> 9;
            in = isW ? w_out : (w_qkv + (size_t)2048 * 1024);
            out = isW ? WoB : (WallB + (size_t)512 * 1024);
            i = (sub & 511) * 2048 + threadIdx.x * 8;
        }
        float4 a = *(const float4*)(in + i);
        float4 b = *(const float4*)(in + i + 4);
        uint4 o;
        o.x = pack2(a.x, a.y); o.y = pack2(a.z, a.w);
        o.z = pack2(b.x, b.y); o.w = pack2(b.z, b.w);
        *(uint4*)(out + i) = o;
    } else {
        const int sub = bid - 3072;      // 0..127
        const int isK = sub >> 6;
        const int h   = (sub >> 2) & 15;
        const int eq  = sub & 3;
        const int e   = eq * 256 + threadIdx.x;
        __shared__ __align__(16) float cs[C_][HD_];   // code[h] slice, 4 KB
        {
            float* csf = &cs[0][0];
            *(float4*)(csf + threadIdx.x * 4) =
                *(const float4*)(code + h * 1024 + threadIdx.x * 4);
        }
        __syncthreads();
        const float* wbase = w_qkv + ((size_t)(isK * D_ + h * HD_)) * D_ + e;
        float acc[C_];
        #pragma unroll
        for (int c = 0; c < C_; ++c) acc[c] = 0.f;
        #pragma unroll 4
        for (int db = 0; db < 16; ++db) {
            const float w0 = wbase[(size_t)(db * 4 + 0) * D_];
            const float w1 = wbase[(size_t)(db * 4 + 1) * D_];
            const float w2 = wbase[(size_t)(db * 4 + 2) * D_];
            const float w3 = wbase[(size_t)(db * 4 + 3) * D_];
            #pragma unroll
            for (int c = 0; c < C_; ++c) {
                float4 cv = *(const float4*)&cs[c][db * 4];
                acc[c] += w0 * cv.x; acc[c] += w1 * cv.y;
                acc[c] += w2 * cv.z; acc[c] += w3 * cv.w;
            }
        }
        ushort* outp = WallB + (size_t)(isK * 256 + h * 16) * D_ + e;
        #pragma unroll
        for (int c = 0; c < C_; ++c)
            outp[(size_t)c * D_] = f2b(acc[c] * SCALE_);
    }
}

// ---------------------------------------------------------------------------
// bf16 MFMA GEMM: C[M,N] = A[M,K] @ B[N,K]^T.
// Tile 128x64 (BM x BN), BK=64, 4 waves (wave-tile 32x64, acc 2x4).
// MODE 0: fp32 C (pitch N).
// MODE 2: gemm1 fused output: cols<512 -> qkcv bf16 (pitch 512);
//         cols>=512 are v -> written TRANSPOSED to vT[bh][d][t].
template<int MODE>
__global__ __launch_bounds__(256)
void gemm_bf16_kernel(const ushort* __restrict__ A, const ushort* __restrict__ Bw,
                      void* __restrict__ Cv, ushort* __restrict__ vTout,
                      int M, int N, int K) {
    __shared__ ushort As[2][128 * 64];   // 2 x 16 KB
    __shared__ ushort Bs[2][64 * 64];    // 2 x 8 KB
    const int tid  = threadIdx.x;
    const int wave = tid >> 6;
    const int lane = tid & 63;

    // XCD swizzle: contiguous tile chunk per XCD (bijective: nwg % 8 == 0)
    const int gx = gridDim.x;
    int f = blockIdx.y * gx + blockIdx.x;
    const int nwg = gx * gridDim.y;
    if ((nwg & 7) == 0) f = (f & 7) * (nwg >> 3) + (f >> 3);
    const int row0 = (f / gx) * 128;
    const int col0 = (f % gx) * 64;

    f32x4 acc[2][4];
    #pragma unroll
    for (int m = 0; m < 2; ++m)
        #pragma unroll
        for (int n = 0; n < 4; ++n) acc[m][n] = (f32x4){0.f, 0.f, 0.f, 0.f};

    // staging constants: linear LDS dest, pre-swizzled global source
    const int srow = lane >> 3;
    const int kA   = ((lane & 7) ^ srow) << 3;
    // fragment-read constants
    const int lane15 = lane & 15;
    const int lhi    = lane >> 4;
    const int axor   = (lane15 & 7) << 4;

    const int NT = K >> 6;

    // stage: 24 segs total (A:16, B:8), 6 per wave
    auto STAGE = [&](int buf, int kk) {
        #pragma unroll
        for (int i = 0; i < 6; ++i) {
            const int sg = wave * 6 + i;
            if (sg < 16) {
                const int r = sg * 8 + srow;
                gll16(A + (size_t)(row0 + r) * K + kk + kA, &As[buf][sg * 512]);
            } else {
                const int sb = sg - 16;
                const int r = sb * 8 + srow;
                gll16(Bw + (size_t)(col0 + r) * K + kk + kA, &Bs[buf][sb * 512]);
            }
        }
    };

    STAGE(0, 0);
    __syncthreads();

    for (int it = 0; it < NT; ++it) {
        const int cur = it & 1;
        if (it + 1 < NT) STAGE(cur ^ 1, (it + 1) << 6);
        const char* Ab = (const char*)As[cur];
        const char* Bb = (const char*)Bs[cur];
        #pragma unroll
        for (int s = 0; s < 2; ++s) {
            short8 af[2], bf[4];
            #pragma unroll
            for (int m = 0; m < 2; ++m) {
                const int r = wave * 32 + m * 16 + lane15;
                const int off = (r * 128 + s * 64 + lhi * 16) ^ axor;
                af[m] = *(const short8*)(Ab + off);
            }
            #pragma unroll
            for (int n = 0; n < 4; ++n) {
                const int r = n * 16 + lane15;
                const int off = (r * 128 + s * 64 + lhi * 16) ^ axor;
                bf[n] = *(const short8*)(Bb + off);
            }
            #pragma unroll
            for (int m = 0; m < 2; ++m)
                #pragma unroll
                for (int n = 0; n < 4; ++n)
                    acc[m][n] = __builtin_amdgcn_mfma_f32_16x16x32_bf16(
                        af[m], bf[n], acc[m][n], 0, 0, 0);
        }
        __syncthreads();   // drains prefetch (vmcnt 0) + protects buffers
    }

    // epilogue: C/D map col=lane&15, row=(lane>>4)*4+j
    #pragma unroll
    for (int m = 0; m < 2; ++m) {
        #pragma unroll
        for (int n = 0; n < 4; ++n) {
            const int row = row0 + wave * 32 + m * 16 + lhi * 4;
            const int col = col0 + n * 16 + lane15;
            if (MODE == 0) {
                float* C = (float*)Cv;
                #pragma unroll
                for (int j = 0; j < 4; ++j)
                    C[(size_t)(row + j) * N + col] = acc[m][n][j];
            } else {   // MODE 2
                if (col0 < 512) {
                    ushort* C = (ushort*)Cv;
                    #pragma unroll
                    for (int j = 0; j < 4; ++j)
                        C[(size_t)(row + j) * QKP_ + col] = f2b(acc[m][n][j]);
                } else {
                    const int dg = col - 512;
                    const int h = dg >> 6, d = dg & 63;
                    const int b = row >> 11;
                    const int t = row & 2047;
                    ushort* p = vTout + ((size_t)((b * 16 + h) * 64 + d)) * 2048 + t;
                    *(uint2*)p = make_uint2(pack2(acc[m][n][0], acc[m][n][1]),
                                            pack2(acc[m][n][2], acc[m][n][3]));
                }
            }
        }
    }
}

// ---------------------------------------------------------------------------
// Chunk-local sums, 512 threads (MFMA kv): per (b,h,chunk):
//   waves 0-3: kv_loc[d][c] = sum_t v[t,d]*ke[t,c]  via 16 MFMAs (keT transpose)
//   waves 4-7: ke_loc[c]    = sum_t ke[t,c]
__global__ __launch_bounds__(512)
void prep_attn_kernel(const ushort* __restrict__ qkcv, const ushort* __restrict__ vT,
                      float* __restrict__ ke_loc, float* __restrict__ kv_loc) {
    const int bid = blockIdx.x;            // bh*NC_ + chunk
    const int chunk = bid & (NC_ - 1);
    const int bh = bid >> 4;
    const int b = bh >> 4, h = bh & 15;
    const int t0 = chunk * L_;
    const int tid = threadIdx.x;
    const int wave = tid >> 6, lane = tid & 63;
    const int l15 = lane & 15, lhi = lane >> 4;

    __shared__ __align__(16) ushort ke_bf[128 * 32];   // 8 KB, swz ((t>>1)&3)<<4
    __shared__ __align__(16) ushort keTs[16 * 128];    // 4 KB, [c][t] swz ^(c<<4)
    __shared__ __align__(16) ushort Vt_s[64 * 128];    // 16 KB, [d][s] swz (d&15)<<4
    __shared__ float gsum[16][16];
    char* keB = (char*)ke_bf;
    char* keT = (char*)keTs;
    char* vtB = (char*)Vt_s;

    // ---- stage ke = exp(kc) bf16 (swizzled + transposed copies) ----
    if (tid < 256) {
        const int t = tid >> 1, c0 = (tid & 1) * 8;
        uint4 raw = *(const uint4*)(qkcv + (size_t)(b * T_ + t0 + t) * QKP_ + 256 + h * C_ + c0);
        float f[8]; unpack8(raw, f);
        float ef[8];
        #pragma unroll
        for (int j = 0; j < 8; ++j) ef[j] = __expf(f[j]);
        uint4 o;
        o.x = pack2(ef[0], ef[1]); o.y = pack2(ef[2], ef[3]);
        o.z = pack2(ef[4], ef[5]); o.w = pack2(ef[6], ef[7]);
        const int swz = ((t >> 1) & 3) << 4;
        *(uint4*)(keB + ((t * 64 + c0 * 2) ^ swz)) = o;
        *(uint4*)(keB + ((t * 64 + 32 + c0 * 2) ^ swz)) = make_uint4(0, 0, 0, 0);
        #pragma unroll
        for (int j = 0; j < 8; ++j) {
            const int c = c0 + j;
            *(ushort*)(keT + (((c << 8) + (t << 1)) ^ (c << 4))) = f2b(ef[j]);
        }
    }
    // ---- stage Vt (bf16 [d][s] swizzled) from vT global, all 512 threads ----
    {
        const int d = tid >> 3, qq = tid & 7;
        const ushort* src = vT + ((size_t)bh * 64 + d) * 2048 + t0 + qq * 16;
        const int swz = (d & 15) << 4;
        #pragma unroll
        for (int ii = 0; ii < 2; ++ii) {
            uint4 raw = *(const uint4*)(src + ii * 8);
            *(uint4*)(vtB + ((d * 256 + qq * 32 + ii * 16) ^ swz)) = raw;
        }
    }
    __syncthreads();

    // ---- waves 0-3: kv^T[d][c] via MFMA; waves 4-7: ke column partial sums ----
    if (wave < 4) {
        const int dt = wave;
        f32x4 kacc = (f32x4){0.f, 0.f, 0.f, 0.f};
        #pragma unroll
        for (int ks = 0; ks < 4; ++ks) {
            const int d = dt * 16 + l15;
            short8 av = *(const short8*)(vtB + ((d * 256 + ks * 64 + lhi * 16) ^ ((d & 15) << 4)));
            short8 bk = *(const short8*)(keT + (((l15 << 8) + ks * 64 + lhi * 16) ^ (l15 << 4)));
            kacc = __builtin_amdgcn_mfma_f32_16x16x32_bf16(av, bk, kacc, 0, 0, 0);
        }
        float* kvb = kv_loc + (size_t)bid * 1024;
        #pragma unroll
        for (int j = 0; j < 4; ++j)
            kvb[(dt * 16 + lhi * 4 + j) * 16 + l15] = kacc[j];
    } else {
        const int cc = tid & 15, g = (tid >> 4) & 15;
        float s = 0.f;
        #pragma unroll
        for (int u = 0; u < 8; ++u) {
            const int t = g * 8 + u;
            s += b2f(*(const ushort*)(keB + ((t * 64 + cc * 2) ^ (((t >> 1) & 3) << 4))));
        }
        gsum[cc][g] = s;
    }
    __syncthreads();
    if (tid < 16) {
        float s = 0.f;
        #pragma unroll
        for (int g = 0; g < 16; ++g) s += gsum[tid][g];
        ke_loc[(size_t)bid * C_ + tid] = s;
    }
}

// ---------------------------------------------------------------------------
// MFMA intra, 8 waves (512 threads): per (b,h,chunk):
//   exclusive chunk-prefix of ke_loc/kv_loc computed in-kernel (sum ch<chunk)
//   P^T = Ke·Qn^T (one s-block per wave), causal mask, P -> swizzled LDS bf16
//   O = Qn·S0 + P·V  (one t-tile per wave; V from GEMM-produced vT)
__global__ __launch_bounds__(512)
void intra_kernel(const ushort* __restrict__ qkcv, const ushort* __restrict__ vT,
                  const float* __restrict__ ke_loc, const float* __restrict__ kv_loc,
                  ushort* __restrict__ xob) {
    const int bid = blockIdx.x;
    const int chunk = bid & (NC_ - 1);
    const int bh = bid >> 4;
    const int b = bh >> 4, h = bh & 15;
    const int t0 = chunk * L_;
    const int tid = threadIdx.x;
    const int wave = tid >> 6, lane = tid & 63;
    const int l15 = lane & 15, lhi = lane >> 4;

    __shared__ __align__(16) ushort ke_bf[128 * 32];
    __shared__ __align__(16) ushort qn_bf[128 * 32];
    __shared__ __align__(16) ushort Vt_s[64 * 128];
    __shared__ __align__(16) ushort Pl[128 * 128];
    __shared__ __align__(16) ushort S0t[64 * 32];
    __shared__ float kesum_s[128][16];
    __shared__ float gsum[16][16];
    __shared__ float e0s[16];

    char* keB = (char*)ke_bf;
    char* qnB = (char*)qn_bf;
    char* vtB = (char*)Vt_s;
    char* plB = (char*)Pl;
    char* s0B = (char*)S0t;

    // ---- stage ke = exp(kc) as bf16 (+ zero pad) ----
    if (tid < 256) {
        const int t = tid >> 1, c0 = (tid & 1) * 8;
        uint4 raw = *(const uint4*)(qkcv + (size_t)(b * T_ + t0 + t) * QKP_ + 256 + h * C_ + c0);
        float f[8]; unpack8(raw, f);
        uint4 o;
        o.x = pack2(__expf(f[0]), __expf(f[1]));
        o.y = pack2(__expf(f[2]), __expf(f[3]));
        o.z = pack2(__expf(f[4]), __expf(f[5]));
        o.w = pack2(__expf(f[6]), __expf(f[7]));
        const int swz = ((t >> 1) & 3) << 4;
        *(uint4*)(keB + ((t * 64 + c0 * 2) ^ swz)) = o;
        *(uint4*)(keB + ((t * 64 + 32 + c0 * 2) ^ swz)) = make_uint4(0, 0, 0, 0);
    }
    // ---- stage Vt (bf16 [d][s] swizzled) from vT global, all 512 threads ----
    {
        const int d = tid >> 3, qq = tid & 7;
        const ushort* src = vT + ((size_t)bh * 64 + d) * 2048 + t0 + qq * 16;
        const int swz = (d & 15) << 4;
        #pragma unroll
        for (int ii = 0; ii < 2; ++ii) {
            uint4 raw = *(const uint4*)(src + ii * 8);
            *(uint4*)(vtB + ((d * 256 + qq * 32 + ii * 16) ^ swz)) = raw;
        }
    }
    // ---- exclusive chunk-prefix: S0t[d][c] = sum_{ch<chunk} kv_loc[ch][d][c] ----
    if (tid < 256) {
        const int d = tid >> 2;
        const int c0 = (tid & 3) * 4;
        const float* base = kv_loc + (size_t)(bh * NC_) * 1024 + d * 16 + c0;
        float s0 = 0.f, s1 = 0.f, s2 = 0.f, s3 = 0.f;
        for (int ch = 0; ch < chunk; ++ch) {
            float4 t4 = *(const float4*)(base + ch * 1024);
            s0 += t4.x; s1 += t4.y; s2 += t4.z; s3 += t4.w;
        }
        const int swz2 = ((d >> 1) & 3) << 4;
        *(uint2*)(s0B + ((d * 64 + c0 * 2) ^ swz2)) =
            make_uint2(pack2(s0, s1), pack2(s2, s3));
        // zero-pad cols 16..31 (bytes 32..63)
        *(uint2*)(s0B + ((d * 64 + 32 + (tid & 3) * 8) ^ swz2)) = make_uint2(0, 0);
    }
    if (tid < 16) {
        float s = 0.f;
        for (int ch = 0; ch < chunk; ++ch)
            s += ke_loc[(size_t)(bh * NC_ + ch) * C_ + tid];
        e0s[tid] = s;
    }
    __syncthreads();

    // ---- two-level inclusive prefix of ke over t (+ e0) -> kesum_s ----
    if (tid < 256) {
        const int cc = tid & 15, g = tid >> 4;
        float s = 0.f;
        #pragma unroll
        for (int u = 0; u < 8; ++u) {
            const int t = g * 8 + u;
            s += b2f(*(const ushort*)(keB + ((t * 64 + cc * 2) ^ (((t >> 1) & 3) << 4))));
        }
        gsum[cc][g] = s;
    }
    __syncthreads();
    if (tid < 16) {
        float run = e0s[tid];
        #pragma unroll
        for (int g = 0; g < 16; ++g) { float tmp = gsum[tid][g]; gsum[tid][g] = run; run += tmp; }
    }
    __syncthreads();
    if (tid < 256) {
        const int cc = tid & 15, g = tid >> 4;
        float run = gsum[cc][g];
        #pragma unroll
        for (int u = 0; u < 8; ++u) {
            const int t = g * 8 + u;
            run += b2f(*(const ushort*)(keB + ((t * 64 + cc * 2) ^ (((t >> 1) & 3) << 4))));
            kesum_s[t][cc] = run;
        }
    }
    __syncthreads();

    // ---- qn = softmax(qc)*scale/(kesum+eps), bf16 (+ zero pad) ----
    if (tid < 128) {
        const int t = tid;
        const ushort* qrow = qkcv + (size_t)(b * T_ + t0 + t) * QKP_ + h * C_;
        float qv[16];
        uint4 r0 = *(const uint4*)qrow, r1 = *(const uint4*)(qrow + 8);
        unpack8(r0, qv); unpack8(r1, qv + 8);
        float m = qv[0];
        #pragma unroll
        for (int c = 1; c < 16; ++c) m = fmaxf(m, qv[c]);
        float sum = 0.f;
        #pragma unroll
        for (int c = 0; c < 16; ++c) { qv[c] = __expf(qv[c] - m); sum += qv[c]; }
        const float inv = SCALE_ / sum;
        #pragma unroll
        for (int c = 0; c < 16; ++c) qv[c] = qv[c] * inv / (kesum_s[t][c] + 1e-9f);
        uint4 o0, o1;
        o0.x = pack2(qv[0], qv[1]);   o0.y = pack2(qv[2], qv[3]);
        o0.z = pack2(qv[4], qv[5]);   o0.w = pack2(qv[6], qv[7]);
        o1.x = pack2(qv[8], qv[9]);   o1.y = pack2(qv[10], qv[11]);
        o1.z = pack2(qv[12], qv[13]); o1.w = pack2(qv[14], qv[15]);
        const int swz = ((t >> 1) & 3) << 4;
        *(uint4*)(qnB + ((t * 64) ^ swz)) = o0;
        *(uint4*)(qnB + ((t * 64 + 16) ^ swz)) = o1;
        *(uint4*)(qnB + ((t * 64 + 32) ^ swz)) = make_uint4(0, 0, 0, 0);
        *(uint4*)(qnB + ((t * 64 + 48) ^ swz)) = make_uint4(0, 0, 0, 0);
    }
    __syncthreads();

    // ---- QK: one s-block per wave: P^T = Ke·Qn^T, mask, write Pl ----
    {
        const int sb = wave;               // 0..7
        const int s_row = sb * 16 + l15;
        short8 af = *(const short8*)(keB + ((s_row * 64 + lhi * 16) ^ (((s_row >> 1) & 3) << 4)));
        #pragma unroll
        for (int tb = 0; tb < 8; ++tb) {
            f32x4 p = (f32x4){0.f, 0.f, 0.f, 0.f};
            if (tb >= sb) {
                const int t_col = tb * 16 + l15;
                short8 bf = *(const short8*)(qnB + ((t_col * 64 + lhi * 16) ^ (((t_col >> 1) & 3) << 4)));
                p = __builtin_amdgcn_mfma_f32_16x16x32_bf16(af, bf, p, 0, 0, 0);
                if (tb == sb) {
                    #pragma unroll
                    for (int j = 0; j < 4; ++j)
                        p[j] = (lhi * 4 + j > l15) ? 0.f : p[j];
                }
            }
            const int t_g = tb * 16 + l15;
            const int sbase = sb * 16 + lhi * 4;
            const int swz = (t_g & 15) << 4;
            *(uint32_t*)(plB + ((t_g * 256 + sbase * 2) ^ swz)) = pack2(p[0], p[1]);
            *(uint32_t*)(plB + ((t_g * 256 + sbase * 2 + 4) ^ swz)) = pack2(p[2], p[3]);
        }
    }
    __syncthreads();

    // ---- O = Qn·S0 + P·V : one t-tile per wave ----
    f32x4 acc4[4];
    #pragma unroll
    for (int dt = 0; dt < 4; ++dt) acc4[dt] = (f32x4){0.f, 0.f, 0.f, 0.f};

    {
        const int t_g = wave * 16 + l15;
        short8 aq = *(const short8*)(qnB + ((t_g * 64 + lhi * 16) ^ (((t_g >> 1) & 3) << 4)));
        #pragma unroll
        for (int dt = 0; dt < 4; ++dt) {
            const int d = dt * 16 + l15;
            short8 bs = *(const short8*)(s0B + ((d * 64 + lhi * 16) ^ (((d >> 1) & 3) << 4)));
            acc4[dt] = __builtin_amdgcn_mfma_f32_16x16x32_bf16(aq, bs, acc4[dt], 0, 0, 0);
        }
        const int pswz = (t_g & 15) << 4;
        #pragma unroll
        for (int kb = 0; kb < 4; ++kb) {
            short8 ap = *(const short8*)(plB + ((t_g * 256 + kb * 64 + lhi * 16) ^ pswz));
            #pragma unroll
            for (int dt = 0; dt < 4; ++dt) {
                const int d = dt * 16 + l15;
                short8 bv = *(const short8*)(vtB + ((d * 256 + kb * 64 + lhi * 16) ^ ((d & 15) << 4)));
                acc4[dt] = __builtin_amdgcn_mfma_f32_16x16x32_bf16(ap, bv, acc4[dt], 0, 0, 0);
            }
        }
    }

    // ---- epilogue ----
    {
        const int tg0 = t0 + wave * 16 + lhi * 4;
        #pragma unroll
        for (int dt = 0; dt < 4; ++dt) {
            const int d = dt * 16 + l15;
            ushort* orow = xob + (size_t)(b * T_ + tg0) * D_ + h * HD_ + d;
            #pragma unroll
            for (int j = 0; j < 4; ++j)
                orow[(size_t)j * D_] = f2b(acc4[dt][j]);
        }
    }
}

// ---------------------------------------------------------------------------
extern "C" void kernel_launch(void* const* d_in, const int* in_sizes, int n_in,
                              void* d_out, int out_size, void* d_ws, size_t ws_size,
                              hipStream_t stream) {
    const float* x     = (const float*)d_in[0];   // (2,2048,1024)
    const float* w_qkv = (const float*)d_in[1];   // (3072,1024)
    const float* w_out = (const float*)d_in[2];   // (1024,1024)
    const float* code  = (const float*)d_in[3];   // (1,16,16,64)
    float* out = (float*)d_out;                   // (2,2048,1024)

    ushort* xb    = (ushort*)d_ws;                    // 4096*1024
    ushort* WallB = xb + (size_t)4096 * 1024;         // 1536*1024
    ushort* WoB   = WallB + (size_t)1536 * 1024;      // 1024*1024
    ushort* qkcv  = WoB + (size_t)1024 * 1024;        // 4096*512 (qc|kc)
    ushort* xob   = qkcv + (size_t)4096 * 512;        // 4096*1024
    ushort* vT    = xob + (size_t)4096 * 1024;        // 32*64*2048
    float*  ke_loc = (float*)(vT + (size_t)32 * 64 * 2048);  // 512*16
    float*  kv_loc = ke_loc + 512 * 16;               // 512*1024 ([d][c] per chunk)

    // merged casts + weight folding (one launch)
    prep_inputs_kernel<<<3200, 256, 0, stream>>>(x, w_qkv, w_out, code, xb, WallB, WoB);

    // fused qc|kc|v projection: (4096 x 1536 x 1024); qc/kc -> qkcv, v -> vT (transposed)
    gemm_bf16_kernel<2><<<dim3(24, 32), 256, 0, stream>>>(xb, WallB, qkcv, vT, 4096, 1536, 1024);

    // chunk-local sums via MFMA (locals only; prefix in intra)
    prep_attn_kernel<<<512, 512, 0, stream>>>(qkcv, vT, ke_loc, kv_loc);
    intra_kernel<<<512, 512, 0, stream>>>(qkcv, vT, ke_loc, kv_loc, xob);

    // out = xo @ w_out^T  (4096 x 1024 x 1024), fp32 out
    gemm_bf16_kernel<0><<<dim3(16, 32), 256, 0, stream>>>(xob, WoB, out, nullptr, 4096, 1024, 1024);
}

// Round 10
// 76.776 us; speedup vs baseline: 2.3543x; 1.0177x over previous
//
#include <hip/hip_runtime.h>
#include <math.h>

// Problem constants (B=2, T=2048, D=1024, H=16, HD=64, C=16)
#define B_    2
#define T_    2048
#define D_    1024
#define H_    16
#define HD_   64
#define C_    16
#define SCALE_ 0.125f      // HEAD_DIM^-0.5
#define L_    128          // time-chunk length
#define NC_   16           // T_/L_
#define QKP_  512          // qkcv row pitch: [qc(256) | kc(256)]

typedef __attribute__((ext_vector_type(8))) short short8;
typedef __attribute__((ext_vector_type(4))) float f32x4;

__device__ inline float b2f(uint32_t u16) {
    return __uint_as_float(u16 << 16);
}
__device__ inline ushort f2b(float f) {   // RNE
    uint32_t u = __float_as_uint(f);
    return (ushort)((u + 0x7FFFu + ((u >> 16) & 1u)) >> 16);
}
__device__ inline uint32_t pack2(float a, float b) {
    return (uint32_t)f2b(a) | ((uint32_t)f2b(b) << 16);
}
__device__ inline void unpack2(uint32_t w, float& a, float& b) {
    a = b2f(w & 0xffffu); b = __uint_as_float(w & 0xffff0000u);
}
__device__ inline void unpack8(uint4 raw, float* dst) {
    unpack2(raw.x, dst[0], dst[1]);
    unpack2(raw.y, dst[2], dst[3]);
    unpack2(raw.z, dst[4], dst[5]);
    unpack2(raw.w, dst[6], dst[7]);
}
__device__ __forceinline__ void gll16(const ushort* g, ushort* l) {
    __builtin_amdgcn_global_load_lds(
        (const __attribute__((address_space(1))) void*)g,
        (__attribute__((address_space(3))) void*)l, 16, 0, 0);
}

// ---------------------------------------------------------------------------
// Merged input prep: blockIdx ranges
//   [0,2048)    : cast x fp32 -> bf16
//   [2048,3072) : cast Wv / w_out -> bf16
//   [3072,3200) : fold fc_code into q/k slices -> WallB rows 0..511
__global__ __launch_bounds__(256)
void prep_inputs_kernel(const float* __restrict__ x, const float* __restrict__ w_qkv,
                        const float* __restrict__ w_out, const float* __restrict__ code,
                        ushort* __restrict__ xb, ushort* __restrict__ WallB,
                        ushort* __restrict__ WoB) {
    const int bid = blockIdx.x;
    if (bid < 3072) {
        const float* in;
        ushort* out;
        int i;
        if (bid < 2048) {
            in = x; out = xb;
            i = bid * 2048 + threadIdx.x * 8;
        } else {
            const int sub = bid - 2048;
            const int isW = sub >> 9;
            in = isW ? w_out : (w_qkv + (size_t)2048 * 1024);
            out = isW ? WoB : (WallB + (size_t)512 * 1024);
            i = (sub & 511) * 2048 + threadIdx.x * 8;
        }
        float4 a = *(const float4*)(in + i);
        float4 b = *(const float4*)(in + i + 4);
        uint4 o;
        o.x = pack2(a.x, a.y); o.y = pack2(a.z, a.w);
        o.z = pack2(b.x, b.y); o.w = pack2(b.z, b.w);
        *(uint4*)(out + i) = o;
    } else {
        const int sub = bid - 3072;      // 0..127
        const int isK = sub >> 6;
        const int h   = (sub >> 2) & 15;
        const int eq  = sub & 3;
        const int e   = eq * 256 + threadIdx.x;
        __shared__ __align__(16) float cs[C_][HD_];   // code[h] slice, 4 KB
        {
            float* csf = &cs[0][0];
            *(float4*)(csf + threadIdx.x * 4) =
                *(const float4*)(code + h * 1024 + threadIdx.x * 4);
        }
        __syncthreads();
        const float* wbase = w_qkv + ((size_t)(isK * D_ + h * HD_)) * D_ + e;
        float acc[C_];
        #pragma unroll
        for (int c = 0; c < C_; ++c) acc[c] = 0.f;
        #pragma unroll 4
        for (int db = 0; db < 16; ++db) {
            const float w0 = wbase[(size_t)(db * 4 + 0) * D_];
            const float w1 = wbase[(size_t)(db * 4 + 1) * D_];
            const float w2 = wbase[(size_t)(db * 4 + 2) * D_];
            const float w3 = wbase[(size_t)(db * 4 + 3) * D_];
            #pragma unroll
            for (int c = 0; c < C_; ++c) {
                float4 cv = *(const float4*)&cs[c][db * 4];
                acc[c] += w0 * cv.x; acc[c] += w1 * cv.y;
                acc[c] += w2 * cv.z; acc[c] += w3 * cv.w;
            }
        }
        ushort* outp = WallB + (size_t)(isK * 256 + h * 16) * D_ + e;
        #pragma unroll
        for (int c = 0; c < C_; ++c)
            outp[(size_t)c * D_] = f2b(acc[c] * SCALE_);
    }
}

// ---------------------------------------------------------------------------
// bf16 MFMA GEMM: C[M,N] = A[M,K] @ B[N,K]^T.
// Tile 128x64 (BM x BN), BK=64, 4 waves (wave-tile 32x64, acc 2x4).
// MODE 0: fp32 C (pitch N).
// MODE 2: gemm1 fused output (LDS-packed, vectorized stores):
//         cols<512 -> qkcv bf16 (pitch 512); cols>=512 -> vT[bh][d][t] transposed.
template<int MODE>
__global__ __launch_bounds__(256)
void gemm_bf16_kernel(const ushort* __restrict__ A, const ushort* __restrict__ Bw,
                      void* __restrict__ Cv, ushort* __restrict__ vTout,
                      int M, int N, int K) {
    __shared__ ushort As[2][128 * 64];   // 2 x 16 KB
    __shared__ ushort Bs[2][64 * 64];    // 2 x 8 KB
    const int tid  = threadIdx.x;
    const int wave = tid >> 6;
    const int lane = tid & 63;

    // XCD swizzle: contiguous tile chunk per XCD (bijective: nwg % 8 == 0)
    const int gx = gridDim.x;
    int f = blockIdx.y * gx + blockIdx.x;
    const int nwg = gx * gridDim.y;
    if ((nwg & 7) == 0) f = (f & 7) * (nwg >> 3) + (f >> 3);
    const int row0 = (f / gx) * 128;
    const int col0 = (f % gx) * 64;

    f32x4 acc[2][4];
    #pragma unroll
    for (int m = 0; m < 2; ++m)
        #pragma unroll
        for (int n = 0; n < 4; ++n) acc[m][n] = (f32x4){0.f, 0.f, 0.f, 0.f};

    // staging constants: linear LDS dest, pre-swizzled global source
    const int srow = lane >> 3;
    const int kA   = ((lane & 7) ^ srow) << 3;
    // fragment-read constants
    const int lane15 = lane & 15;
    const int lhi    = lane >> 4;
    const int axor   = (lane15 & 7) << 4;

    const int NT = K >> 6;

    // stage: 24 segs total (A:16, B:8), 6 per wave
    auto STAGE = [&](int buf, int kk) {
        #pragma unroll
        for (int i = 0; i < 6; ++i) {
            const int sg = wave * 6 + i;
            if (sg < 16) {
                const int r = sg * 8 + srow;
                gll16(A + (size_t)(row0 + r) * K + kk + kA, &As[buf][sg * 512]);
            } else {
                const int sb = sg - 16;
                const int r = sb * 8 + srow;
                gll16(Bw + (size_t)(col0 + r) * K + kk + kA, &Bs[buf][sb * 512]);
            }
        }
    };

    STAGE(0, 0);
    __syncthreads();

    for (int it = 0; it < NT; ++it) {
        const int cur = it & 1;
        if (it + 1 < NT) STAGE(cur ^ 1, (it + 1) << 6);
        const char* Ab = (const char*)As[cur];
        const char* Bb = (const char*)Bs[cur];
        #pragma unroll
        for (int s = 0; s < 2; ++s) {
            short8 af[2], bf[4];
            #pragma unroll
            for (int m = 0; m < 2; ++m) {
                const int r = wave * 32 + m * 16 + lane15;
                const int off = (r * 128 + s * 64 + lhi * 16) ^ axor;
                af[m] = *(const short8*)(Ab + off);
            }
            #pragma unroll
            for (int n = 0; n < 4; ++n) {
                const int r = n * 16 + lane15;
                const int off = (r * 128 + s * 64 + lhi * 16) ^ axor;
                bf[n] = *(const short8*)(Bb + off);
            }
            #pragma unroll
            for (int m = 0; m < 2; ++m)
                #pragma unroll
                for (int n = 0; n < 4; ++n)
                    acc[m][n] = __builtin_amdgcn_mfma_f32_16x16x32_bf16(
                        af[m], bf[n], acc[m][n], 0, 0, 0);
        }
        __syncthreads();   // drains prefetch (vmcnt 0) + protects buffers
    }

    // epilogue: C/D map col=lane&15, row=(lane>>4)*4+j
    if (MODE == 0) {
        float* C = (float*)Cv;
        #pragma unroll
        for (int m = 0; m < 2; ++m) {
            #pragma unroll
            for (int n = 0; n < 4; ++n) {
                const int row = row0 + wave * 32 + m * 16 + lhi * 4;
                const int col = col0 + n * 16 + lane15;
                #pragma unroll
                for (int j = 0; j < 4; ++j)
                    C[(size_t)(row + j) * N + col] = acc[m][n][j];
            }
        }
    } else {
        // MODE 2: pack tile into dead As LDS, then vectorized global stores.
        ushort* pk = (ushort*)As;   // 16 KB reuse (all LDS reads done at last barrier)
        if (col0 < 512) {
            // pack [row_local][col_local] 128x64
            #pragma unroll
            for (int m = 0; m < 2; ++m) {
                #pragma unroll
                for (int n = 0; n < 4; ++n) {
                    const int rl = wave * 32 + m * 16 + lhi * 4;
                    const int cl = n * 16 + lane15;
                    #pragma unroll
                    for (int j = 0; j < 4; ++j)
                        pk[(rl + j) * 64 + cl] = f2b(acc[m][n][j]);
                }
            }
            __syncthreads();
            ushort* C = (ushort*)Cv;
            #pragma unroll
            for (int i = 0; i < 4; ++i) {
                const int u = tid + i * 256;
                const int r = u >> 3, c8 = (u & 7) * 8;
                *(uint4*)(C + (size_t)(row0 + r) * QKP_ + col0 + c8) =
                    *(const uint4*)(pk + r * 64 + c8);
            }
        } else {
            // pack transposed [d_local][t_local] 64x128 with 16B-granule XOR swizzle
            char* pkB = (char*)pk;
            #pragma unroll
            for (int m = 0; m < 2; ++m) {
                #pragma unroll
                for (int n = 0; n < 4; ++n) {
                    const int rl = wave * 32 + m * 16 + lhi * 4;   // t_local (4 consecutive j)
                    const int dl = n * 16 + lane15;                // d_local
                    const int off = (dl * 256 + rl * 2) ^ ((dl & 7) << 4);
                    *(uint2*)(pkB + off) = make_uint2(
                        pack2(acc[m][n][0], acc[m][n][1]),
                        pack2(acc[m][n][2], acc[m][n][3]));
                }
            }
            __syncthreads();
            const int h  = (col0 - 512) >> 6;
            const int bb = row0 >> 11;
            const int t0l = row0 & 2047;
            #pragma unroll
            for (int i = 0; i < 4; ++i) {
                const int u = tid + i * 256;
                const int d = u >> 4, t8 = (u & 15) * 8;
                const int off = (d * 256 + t8 * 2) ^ ((d & 7) << 4);
                *(uint4*)(vTout + ((size_t)((bb * 16 + h) * 64 + d)) * 2048 + t0l + t8) =
                    *(const uint4*)(pkB + off);
            }
        }
    }
}

// ---------------------------------------------------------------------------
// Chunk-local sums, 512 threads (MFMA kv): per (b,h,chunk):
//   waves 0-3: kv_loc[d][c] = sum_t v[t,d]*ke[t,c]  via 16 MFMAs (keT transpose)
//   waves 4-7: ke_loc[c]    = sum_t ke[t,c]
__global__ __launch_bounds__(512)
void prep_attn_kernel(const ushort* __restrict__ qkcv, const ushort* __restrict__ vT,
                      float* __restrict__ ke_loc, float* __restrict__ kv_loc) {
    const int bid = blockIdx.x;            // bh*NC_ + chunk
    const int chunk = bid & (NC_ - 1);
    const int bh = bid >> 4;
    const int b = bh >> 4, h = bh & 15;
    const int t0 = chunk * L_;
    const int tid = threadIdx.x;
    const int wave = tid >> 6, lane = tid & 63;
    const int l15 = lane & 15, lhi = lane >> 4;

    __shared__ __align__(16) ushort ke_bf[128 * 32];   // 8 KB, swz ((t>>1)&3)<<4
    __shared__ __align__(16) ushort keTs[16 * 128];    // 4 KB, [c][t] swz ^(c<<4)
    __shared__ __align__(16) ushort Vt_s[64 * 128];    // 16 KB, [d][s] swz (d&15)<<4
    __shared__ float gsum[16][16];
    char* keB = (char*)ke_bf;
    char* keT = (char*)keTs;
    char* vtB = (char*)Vt_s;

    // ---- stage ke = exp(kc) bf16 (swizzled + transposed copies) ----
    if (tid < 256) {
        const int t = tid >> 1, c0 = (tid & 1) * 8;
        uint4 raw = *(const uint4*)(qkcv + (size_t)(b * T_ + t0 + t) * QKP_ + 256 + h * C_ + c0);
        float f[8]; unpack8(raw, f);
        float ef[8];
        #pragma unroll
        for (int j = 0; j < 8; ++j) ef[j] = __expf(f[j]);
        uint4 o;
        o.x = pack2(ef[0], ef[1]); o.y = pack2(ef[2], ef[3]);
        o.z = pack2(ef[4], ef[5]); o.w = pack2(ef[6], ef[7]);
        const int swz = ((t >> 1) & 3) << 4;
        *(uint4*)(keB + ((t * 64 + c0 * 2) ^ swz)) = o;
        *(uint4*)(keB + ((t * 64 + 32 + c0 * 2) ^ swz)) = make_uint4(0, 0, 0, 0);
        #pragma unroll
        for (int j = 0; j < 8; ++j) {
            const int c = c0 + j;
            *(ushort*)(keT + (((c << 8) + (t << 1)) ^ (c << 4))) = f2b(ef[j]);
        }
    }
    // ---- stage Vt (bf16 [d][s] swizzled) from vT global, all 512 threads ----
    {
        const int d = tid >> 3, qq = tid & 7;
        const ushort* src = vT + ((size_t)bh * 64 + d) * 2048 + t0 + qq * 16;
        const int swz = (d & 15) << 4;
        #pragma unroll
        for (int ii = 0; ii < 2; ++ii) {
            uint4 raw = *(const uint4*)(src + ii * 8);
            *(uint4*)(vtB + ((d * 256 + qq * 32 + ii * 16) ^ swz)) = raw;
        }
    }
    __syncthreads();

    // ---- waves 0-3: kv^T[d][c] via MFMA; waves 4-7: ke column partial sums ----
    if (wave < 4) {
        const int dt = wave;
        f32x4 kacc = (f32x4){0.f, 0.f, 0.f, 0.f};
        #pragma unroll
        for (int ks = 0; ks < 4; ++ks) {
            const int d = dt * 16 + l15;
            short8 av = *(const short8*)(vtB + ((d * 256 + ks * 64 + lhi * 16) ^ ((d & 15) << 4)));
            short8 bk = *(const short8*)(keT + (((l15 << 8) + ks * 64 + lhi * 16) ^ (l15 << 4)));
            kacc = __builtin_amdgcn_mfma_f32_16x16x32_bf16(av, bk, kacc, 0, 0, 0);
        }
        float* kvb = kv_loc + (size_t)bid * 1024;
        #pragma unroll
        for (int j = 0; j < 4; ++j)
            kvb[(dt * 16 + lhi * 4 + j) * 16 + l15] = kacc[j];
    } else {
        const int cc = tid & 15, g = (tid >> 4) & 15;
        float s = 0.f;
        #pragma unroll
        for (int u = 0; u < 8; ++u) {
            const int t = g * 8 + u;
            s += b2f(*(const ushort*)(keB + ((t * 64 + cc * 2) ^ (((t >> 1) & 3) << 4))));
        }
        gsum[cc][g] = s;
    }
    __syncthreads();
    if (tid < 16) {
        float s = 0.f;
        #pragma unroll
        for (int g = 0; g < 16; ++g) s += gsum[tid][g];
        ke_loc[(size_t)bid * C_ + tid] = s;
    }
}

// ---------------------------------------------------------------------------
// MFMA intra, 8 waves (512 threads): per (b,h,chunk):
//   exclusive chunk-prefix of ke_loc/kv_loc computed in-kernel (sum ch<chunk)
//   P^T = Ke·Qn^T (one s-block per wave), causal mask, P -> swizzled LDS bf16
//   O = Qn·S0 + P·V; output packed via Pl -> vectorized stores.
__global__ __launch_bounds__(512)
void intra_kernel(const ushort* __restrict__ qkcv, const ushort* __restrict__ vT,
                  const float* __restrict__ ke_loc, const float* __restrict__ kv_loc,
                  ushort* __restrict__ xob) {
    const int bid = blockIdx.x;
    const int chunk = bid & (NC_ - 1);
    const int bh = bid >> 4;
    const int b = bh >> 4, h = bh & 15;
    const int t0 = chunk * L_;
    const int tid = threadIdx.x;
    const int wave = tid >> 6, lane = tid & 63;
    const int l15 = lane & 15, lhi = lane >> 4;

    __shared__ __align__(16) ushort ke_bf[128 * 32];
    __shared__ __align__(16) ushort qn_bf[128 * 32];
    __shared__ __align__(16) ushort Vt_s[64 * 128];
    __shared__ __align__(16) ushort Pl[128 * 128];
    __shared__ __align__(16) ushort S0t[64 * 32];
    __shared__ float kesum_s[128][16];
    __shared__ float gsum[16][16];
    __shared__ float e0s[16];

    char* keB = (char*)ke_bf;
    char* qnB = (char*)qn_bf;
    char* vtB = (char*)Vt_s;
    char* plB = (char*)Pl;
    char* s0B = (char*)S0t;

    // ---- region 1: stage ke (waves 0-3), Vt (all), e0 (tid<16) ----
    if (tid < 256) {
        const int t = tid >> 1, c0 = (tid & 1) * 8;
        uint4 raw = *(const uint4*)(qkcv + (size_t)(b * T_ + t0 + t) * QKP_ + 256 + h * C_ + c0);
        float f[8]; unpack8(raw, f);
        uint4 o;
        o.x = pack2(__expf(f[0]), __expf(f[1]));
        o.y = pack2(__expf(f[2]), __expf(f[3]));
        o.z = pack2(__expf(f[4]), __expf(f[5]));
        o.w = pack2(__expf(f[6]), __expf(f[7]));
        const int swz = ((t >> 1) & 3) << 4;
        *(uint4*)(keB + ((t * 64 + c0 * 2) ^ swz)) = o;
        *(uint4*)(keB + ((t * 64 + 32 + c0 * 2) ^ swz)) = make_uint4(0, 0, 0, 0);
    }
    {
        const int d = tid >> 3, qq = tid & 7;
        const ushort* src = vT + ((size_t)bh * 64 + d) * 2048 + t0 + qq * 16;
        const int swz = (d & 15) << 4;
        #pragma unroll
        for (int ii = 0; ii < 2; ++ii) {
            uint4 raw = *(const uint4*)(src + ii * 8);
            *(uint4*)(vtB + ((d * 256 + qq * 32 + ii * 16) ^ swz)) = raw;
        }
    }
    if (tid < 16) {
        float s = 0.f;
        for (int ch = 0; ch < chunk; ++ch)
            s += ke_loc[(size_t)(bh * NC_ + ch) * C_ + tid];
        e0s[tid] = s;
    }
    __syncthreads();

    // ---- region 2 (parallel): waves 0-3 S0-prefix; waves 4-7 gsum partials ----
    if (tid < 256) {
        const int d = tid >> 2;
        const int c0 = (tid & 3) * 4;
        const float* base = kv_loc + (size_t)(bh * NC_) * 1024 + d * 16 + c0;
        float s0 = 0.f, s1 = 0.f, s2 = 0.f, s3 = 0.f;
        for (int ch = 0; ch < chunk; ++ch) {
            float4 t4 = *(const float4*)(base + ch * 1024);
            s0 += t4.x; s1 += t4.y; s2 += t4.z; s3 += t4.w;
        }
        const int swz2 = ((d >> 1) & 3) << 4;
        *(uint2*)(s0B + ((d * 64 + c0 * 2) ^ swz2)) =
            make_uint2(pack2(s0, s1), pack2(s2, s3));
        // zero-pad cols 16..31 (bytes 32..63)
        *(uint2*)(s0B + ((d * 64 + 32 + (tid & 3) * 8) ^ swz2)) = make_uint2(0, 0);
    } else {
        const int cc = tid & 15, g = (tid >> 4) & 15;
        float s = 0.f;
        #pragma unroll
        for (int u = 0; u < 8; ++u) {
            const int t = g * 8 + u;
            s += b2f(*(const ushort*)(keB + ((t * 64 + cc * 2) ^ (((t >> 1) & 3) << 4))));
        }
        gsum[cc][g] = s;
    }
    __syncthreads();
    if (tid < 16) {
        float run = e0s[tid];
        #pragma unroll
        for (int g = 0; g < 16; ++g) { float tmp = gsum[tid][g]; gsum[tid][g] = run; run += tmp; }
    }
    __syncthreads();
    if (tid < 256) {
        const int cc = tid & 15, g = tid >> 4;
        float run = gsum[cc][g];
        #pragma unroll
        for (int u = 0; u < 8; ++u) {
            const int t = g * 8 + u;
            run += b2f(*(const ushort*)(keB + ((t * 64 + cc * 2) ^ (((t >> 1) & 3) << 4))));
            kesum_s[t][cc] = run;
        }
    }
    __syncthreads();

    // ---- qn = softmax(qc)*scale/(kesum+eps), bf16 (+ zero pad) ----
    if (tid < 128) {
        const int t = tid;
        const ushort* qrow = qkcv + (size_t)(b * T_ + t0 + t) * QKP_ + h * C_;
        float qv[16];
        uint4 r0 = *(const uint4*)qrow, r1 = *(const uint4*)(qrow + 8);
        unpack8(r0, qv); unpack8(r1, qv + 8);
        float m = qv[0];
        #pragma unroll
        for (int c = 1; c < 16; ++c) m = fmaxf(m, qv[c]);
        float sum = 0.f;
        #pragma unroll
        for (int c = 0; c < 16; ++c) { qv[c] = __expf(qv[c] - m); sum += qv[c]; }
        const float inv = SCALE_ / sum;
        #pragma unroll
        for (int c = 0; c < 16; ++c) qv[c] = qv[c] * inv / (kesum_s[t][c] + 1e-9f);
        uint4 o0, o1;
        o0.x = pack2(qv[0], qv[1]);   o0.y = pack2(qv[2], qv[3]);
        o0.z = pack2(qv[4], qv[5]);   o0.w = pack2(qv[6], qv[7]);
        o1.x = pack2(qv[8], qv[9]);   o1.y = pack2(qv[10], qv[11]);
        o1.z = pack2(qv[12], qv[13]); o1.w = pack2(qv[14], qv[15]);
        const int swz = ((t >> 1) & 3) << 4;
        *(uint4*)(qnB + ((t * 64) ^ swz)) = o0;
        *(uint4*)(qnB + ((t * 64 + 16) ^ swz)) = o1;
        *(uint4*)(qnB + ((t * 64 + 32) ^ swz)) = make_uint4(0, 0, 0, 0);
        *(uint4*)(qnB + ((t * 64 + 48) ^ swz)) = make_uint4(0, 0, 0, 0);
    }
    __syncthreads();

    // ---- QK: one s-block per wave: P^T = Ke·Qn^T, mask, write Pl ----
    {
        const int sb = wave;               // 0..7
        const int s_row = sb * 16 + l15;
        short8 af = *(const short8*)(keB + ((s_row * 64 + lhi * 16) ^ (((s_row >> 1) & 3) << 4)));
        #pragma unroll
        for (int tb = 0; tb < 8; ++tb) {
            f32x4 p = (f32x4){0.f, 0.f, 0.f, 0.f};
            if (tb >= sb) {
                const int t_col = tb * 16 + l15;
                short8 bf = *(const short8*)(qnB + ((t_col * 64 + lhi * 16) ^ (((t_col >> 1) & 3) << 4)));
                p = __builtin_amdgcn_mfma_f32_16x16x32_bf16(af, bf, p, 0, 0, 0);
                if (tb == sb) {
                    #pragma unroll
                    for (int j = 0; j < 4; ++j)
                        p[j] = (lhi * 4 + j > l15) ? 0.f : p[j];
                }
            }
            const int t_g = tb * 16 + l15;
            const int sbase = sb * 16 + lhi * 4;
            const int swz = (t_g & 15) << 4;
            *(uint32_t*)(plB + ((t_g * 256 + sbase * 2) ^ swz)) = pack2(p[0], p[1]);
            *(uint32_t*)(plB + ((t_g * 256 + sbase * 2 + 4) ^ swz)) = pack2(p[2], p[3]);
        }
    }
    __syncthreads();

    // ---- O = Qn·S0 + P·V : one t-tile per wave ----
    f32x4 acc4[4];
    #pragma unroll
    for (int dt = 0; dt < 4; ++dt) acc4[dt] = (f32x4){0.f, 0.f, 0.f, 0.f};

    {
        const int t_g = wave * 16 + l15;
        short8 aq = *(const short8*)(qnB + ((t_g * 64 + lhi * 16) ^ (((t_g >> 1) & 3) << 4)));
        #pragma unroll
        for (int dt = 0; dt < 4; ++dt) {
            const int d = dt * 16 + l15;
            short8 bs = *(const short8*)(s0B + ((d * 64 + lhi * 16) ^ (((d >> 1) & 3) << 4)));
            acc4[dt] = __builtin_amdgcn_mfma_f32_16x16x32_bf16(aq, bs, acc4[dt], 0, 0, 0);
        }
        const int pswz = (t_g & 15) << 4;
        #pragma unroll
        for (int kb = 0; kb < 4; ++kb) {
            short8 ap = *(const short8*)(plB + ((t_g * 256 + kb * 64 + lhi * 16) ^ pswz));
            #pragma unroll
            for (int dt = 0; dt < 4; ++dt) {
                const int d = dt * 16 + l15;
                short8 bv = *(const short8*)(vtB + ((d * 256 + kb * 64 + lhi * 16) ^ ((d & 15) << 4)));
                acc4[dt] = __builtin_amdgcn_mfma_f32_16x16x32_bf16(ap, bv, acc4[dt], 0, 0, 0);
            }
        }
    }

    // ---- epilogue: pack O into dead Pl as [t][d], then vectorized stores ----
    __syncthreads();   // all PV reads of Pl done
    {
        ushort* ob = (ushort*)Pl;
        const int tl = wave * 16 + lhi * 4;
        #pragma unroll
        for (int dt = 0; dt < 4; ++dt) {
            const int d = dt * 16 + l15;
            #pragma unroll
            for (int j = 0; j < 4; ++j)
                ob[(tl + j) * 64 + d] = f2b(acc4[dt][j]);
        }
    }
    __syncthreads();
    {
        const ushort* ob = (const ushort*)Pl;
        #pragma unroll
        for (int i = 0; i < 2; ++i) {
            const int u = tid + i * 512;
            const int t = u >> 3, c8 = (u & 7) * 8;
            *(uint4*)(xob + (size_t)(b * T_ + t0 + t) * D_ + h * HD_ + c8) =
                *(const uint4*)(ob + t * 64 + c8);
        }
    }
}

// ---------------------------------------------------------------------------
extern "C" void kernel_launch(void* const* d_in, const int* in_sizes, int n_in,
                              void* d_out, int out_size, void* d_ws, size_t ws_size,
                              hipStream_t stream) {
    const float* x     = (const float*)d_in[0];   // (2,2048,1024)
    const float* w_qkv = (const float*)d_in[1];   // (3072,1024)
    const float* w_out = (const float*)d_in[2];   // (1024,1024)
    const float* code  = (const float*)d_in[3];   // (1,16,16,64)
    float* out = (float*)d_out;                   // (2,2048,1024)

    ushort* xb    = (ushort*)d_ws;                    // 4096*1024
    ushort* WallB = xb + (size_t)4096 * 1024;         // 1536*1024
    ushort* WoB   = WallB + (size_t)1536 * 1024;      // 1024*1024
    ushort* qkcv  = WoB + (size_t)1024 * 1024;        // 4096*512 (qc|kc)
    ushort* xob   = qkcv + (size_t)4096 * 512;        // 4096*1024
    ushort* vT    = xob + (size_t)4096 * 1024;        // 32*64*2048
    float*  ke_loc = (float*)(vT + (size_t)32 * 64 * 2048);  // 512*16
    float*  kv_loc = ke_loc + 512 * 16;               // 512*1024 ([d][c] per chunk)

    // merged casts + weight folding (one launch)
    prep_inputs_kernel<<<3200, 256, 0, stream>>>(x, w_qkv, w_out, code, xb, WallB, WoB);

    // fused qc|kc|v projection: (4096 x 1536 x 1024); qc/kc -> qkcv, v -> vT (transposed)
    gemm_bf16_kernel<2><<<dim3(24, 32), 256, 0, stream>>>(xb, WallB, qkcv, vT, 4096, 1536, 1024);

    // chunk-local sums via MFMA (locals only; prefix in intra)
    prep_attn_kernel<<<512, 512, 0, stream>>>(qkcv, vT, ke_loc, kv_loc);
    intra_kernel<<<512, 512, 0, stream>>>(qkcv, vT, ke_loc, kv_loc, xob);

    // out = xo @ w_out^T  (4096 x 1024 x 1024), fp32 out
    gemm_bf16_kernel<0><<<dim3(16, 32), 256, 0, stream>>>(xob, WoB, out, nullptr, 4096, 1024, 1024);
}

// Round 11
// 74.898 us; speedup vs baseline: 2.4133x; 1.0251x over previous
//
#include <hip/hip_runtime.h>
#include <math.h>

// Problem constants (B=2, T=2048, D=1024, H=16, HD=64, C=16)
#define B_    2
#define T_    2048
#define D_    1024
#define H_    16
#define HD_   64
#define C_    16
#define SCALE_ 0.125f      // HEAD_DIM^-0.5
#define L_    128          // time-chunk length
#define NC_   16           // T_/L_
#define QKP_  512          // qkcv row pitch: [qc(256) | kc(256)]

typedef __attribute__((ext_vector_type(8))) short short8;
typedef __attribute__((ext_vector_type(4))) float f32x4;

__device__ inline float b2f(uint32_t u16) {
    return __uint_as_float(u16 << 16);
}
__device__ inline ushort f2b(float f) {   // RNE
    uint32_t u = __float_as_uint(f);
    return (ushort)((u + 0x7FFFu + ((u >> 16) & 1u)) >> 16);
}
__device__ inline uint32_t pack2(float a, float b) {
    return (uint32_t)f2b(a) | ((uint32_t)f2b(b) << 16);
}
__device__ inline void unpack2(uint32_t w, float& a, float& b) {
    a = b2f(w & 0xffffu); b = __uint_as_float(w & 0xffff0000u);
}
__device__ inline void unpack8(uint4 raw, float* dst) {
    unpack2(raw.x, dst[0], dst[1]);
    unpack2(raw.y, dst[2], dst[3]);
    unpack2(raw.z, dst[4], dst[5]);
    unpack2(raw.w, dst[6], dst[7]);
}
__device__ __forceinline__ void gll16(const ushort* g, ushort* l) {
    __builtin_amdgcn_global_load_lds(
        (const __attribute__((address_space(1))) void*)g,
        (__attribute__((address_space(3))) void*)l, 16, 0, 0);
}

// ---------------------------------------------------------------------------
// Merged input prep: blockIdx ranges
//   [0,2048)    : cast x fp32 -> bf16
//   [2048,3072) : cast Wv / w_out -> bf16
//   [3072,3200) : fold fc_code into q/k slices -> WallB rows 0..511
__global__ __launch_bounds__(256)
void prep_inputs_kernel(const float* __restrict__ x, const float* __restrict__ w_qkv,
                        const float* __restrict__ w_out, const float* __restrict__ code,
                        ushort* __restrict__ xb, ushort* __restrict__ WallB,
                        ushort* __restrict__ WoB) {
    const int bid = blockIdx.x;
    if (bid < 3072) {
        const float* in;
        ushort* out;
        int i;
        if (bid < 2048) {
            in = x; out = xb;
            i = bid * 2048 + threadIdx.x * 8;
        } else {
            const int sub = bid - 2048;
            const int isW = sub >> 9;
            in = isW ? w_out : (w_qkv + (size_t)2048 * 1024);
            out = isW ? WoB : (WallB + (size_t)512 * 1024);
            i = (sub & 511) * 2048 + threadIdx.x * 8;
        }
        float4 a = *(const float4*)(in + i);
        float4 b = *(const float4*)(in + i + 4);
        uint4 o;
        o.x = pack2(a.x, a.y); o.y = pack2(a.z, a.w);
        o.z = pack2(b.x, b.y); o.w = pack2(b.z, b.w);
        *(uint4*)(out + i) = o;
    } else {
        const int sub = bid - 3072;      // 0..127
        const int isK = sub >> 6;
        const int h   = (sub >> 2) & 15;
        const int eq  = sub & 3;
        const int e   = eq * 256 + threadIdx.x;
        __shared__ __align__(16) float cs[C_][HD_];   // code[h] slice, 4 KB
        {
            float* csf = &cs[0][0];
            *(float4*)(csf + threadIdx.x * 4) =
                *(const float4*)(code + h * 1024 + threadIdx.x * 4);
        }
        __syncthreads();
        const float* wbase = w_qkv + ((size_t)(isK * D_ + h * HD_)) * D_ + e;
        float acc[C_];
        #pragma unroll
        for (int c = 0; c < C_; ++c) acc[c] = 0.f;
        #pragma unroll 4
        for (int db = 0; db < 16; ++db) {
            const float w0 = wbase[(size_t)(db * 4 + 0) * D_];
            const float w1 = wbase[(size_t)(db * 4 + 1) * D_];
            const float w2 = wbase[(size_t)(db * 4 + 2) * D_];
            const float w3 = wbase[(size_t)(db * 4 + 3) * D_];
            #pragma unroll
            for (int c = 0; c < C_; ++c) {
                float4 cv = *(const float4*)&cs[c][db * 4];
                acc[c] += w0 * cv.x; acc[c] += w1 * cv.y;
                acc[c] += w2 * cv.z; acc[c] += w3 * cv.w;
            }
        }
        ushort* outp = WallB + (size_t)(isK * 256 + h * 16) * D_ + e;
        #pragma unroll
        for (int c = 0; c < C_; ++c)
            outp[(size_t)c * D_] = f2b(acc[c] * SCALE_);
    }
}

// ---------------------------------------------------------------------------
// bf16 MFMA GEMM: C[M,N] = A[M,K] @ B[N,K]^T.
// Tile 128x128 (BM x BN), BK=64, 4 waves, wave-tile 64x64 (acc 4x4).
// Rationale (r11): halves L2 staging traffic per output vs 128x64 (32KB/K-step
// for 2x output) and drops ds_read:MFMA to 0.5 (512 < 620 clk/K-step/CU).
// LDS 64KB dbuf -> 2 blocks/CU.
// MODE 0: fp32 C (pitch N).
// MODE 2: gemm1 fused output (LDS-packed, vectorized stores):
//         cols<512 -> qkcv bf16 (pitch 512); cols>=512 -> vT[bh][d][t] transposed.
template<int MODE>
__global__ __launch_bounds__(256)
void gemm_bf16_kernel(const ushort* __restrict__ A, const ushort* __restrict__ Bw,
                      void* __restrict__ Cv, ushort* __restrict__ vTout,
                      int M, int N, int K) {
    __shared__ ushort As[2][128 * 64];   // 2 x 16 KB (contiguous 32KB)
    __shared__ ushort Bs[2][128 * 64];   // 2 x 16 KB
    const int tid  = threadIdx.x;
    const int wave = tid >> 6;
    const int lane = tid & 63;
    const int wr = wave >> 1, wc = wave & 1;

    // XCD swizzle: contiguous tile chunk per XCD (bijective: nwg % 8 == 0)
    const int gx = gridDim.x;
    int f = blockIdx.y * gx + blockIdx.x;
    const int nwg = gx * gridDim.y;
    if ((nwg & 7) == 0) f = (f & 7) * (nwg >> 3) + (f >> 3);
    const int row0 = (f / gx) * 128;
    const int col0 = (f % gx) * 128;

    f32x4 acc[4][4];
    #pragma unroll
    for (int m = 0; m < 4; ++m)
        #pragma unroll
        for (int n = 0; n < 4; ++n) acc[m][n] = (f32x4){0.f, 0.f, 0.f, 0.f};

    // staging constants: linear LDS dest, pre-swizzled global source
    const int srow = lane >> 3;
    const int kA   = ((lane & 7) ^ srow) << 3;
    // fragment-read constants
    const int lane15 = lane & 15;
    const int lhi    = lane >> 4;
    const int axor   = (lane15 & 7) << 4;

    const int NT = K >> 6;

    // stage: 32 segs total (A:16, B:16), 8 per wave
    auto STAGE = [&](int buf, int kk) {
        #pragma unroll
        for (int i = 0; i < 8; ++i) {
            const int sg = wave * 8 + i;
            if (sg < 16) {
                const int r = sg * 8 + srow;
                gll16(A + (size_t)(row0 + r) * K + kk + kA, &As[buf][sg * 512]);
            } else {
                const int sb = sg - 16;
                const int r = sb * 8 + srow;
                gll16(Bw + (size_t)(col0 + r) * K + kk + kA, &Bs[buf][sb * 512]);
            }
        }
    };

    STAGE(0, 0);
    __syncthreads();

    for (int it = 0; it < NT; ++it) {
        const int cur = it & 1;
        if (it + 1 < NT) STAGE(cur ^ 1, (it + 1) << 6);
        const char* Ab = (const char*)As[cur];
        const char* Bb = (const char*)Bs[cur];
        #pragma unroll
        for (int s = 0; s < 2; ++s) {
            short8 af[4], bf[4];
            #pragma unroll
            for (int m = 0; m < 4; ++m) {
                const int r = wr * 64 + m * 16 + lane15;
                const int off = (r * 128 + s * 64 + lhi * 16) ^ axor;
                af[m] = *(const short8*)(Ab + off);
            }
            #pragma unroll
            for (int n = 0; n < 4; ++n) {
                const int r = wc * 64 + n * 16 + lane15;
                const int off = (r * 128 + s * 64 + lhi * 16) ^ axor;
                bf[n] = *(const short8*)(Bb + off);
            }
            #pragma unroll
            for (int m = 0; m < 4; ++m)
                #pragma unroll
                for (int n = 0; n < 4; ++n)
                    acc[m][n] = __builtin_amdgcn_mfma_f32_16x16x32_bf16(
                        af[m], bf[n], acc[m][n], 0, 0, 0);
        }
        __syncthreads();   // drains prefetch (vmcnt 0) + protects buffers
    }

    // epilogue: C/D map col=lane&15, row=(lane>>4)*4+j
    if (MODE == 0) {
        float* C = (float*)Cv;
        #pragma unroll
        for (int m = 0; m < 4; ++m) {
            #pragma unroll
            for (int n = 0; n < 4; ++n) {
                const int row = row0 + wr * 64 + m * 16 + lhi * 4;
                const int col = col0 + wc * 64 + n * 16 + lane15;
                #pragma unroll
                for (int j = 0; j < 4; ++j)
                    C[(size_t)(row + j) * N + col] = acc[m][n][j];
            }
        }
    } else {
        // MODE 2: pack 128x128 bf16 tile (32KB) into dead As[2] LDS, then
        // vectorized global stores. XOR row-swizzle avoids read conflicts.
        char* pkB = (char*)As;   // 32 KB contiguous
        if (col0 < 512) {
            // pack [rl][cl], row pitch 256B, swz ^((rl&7)<<4)
            #pragma unroll
            for (int m = 0; m < 4; ++m) {
                #pragma unroll
                for (int n = 0; n < 4; ++n) {
                    const int rl0 = wr * 64 + m * 16 + lhi * 4;
                    const int cl = wc * 64 + n * 16 + lane15;
                    #pragma unroll
                    for (int j = 0; j < 4; ++j) {
                        const int rl = rl0 + j;
                        *(ushort*)(pkB + ((rl * 256 + cl * 2) ^ ((rl & 7) << 4))) =
                            f2b(acc[m][n][j]);
                    }
                }
            }
            __syncthreads();
            ushort* C = (ushort*)Cv;
            #pragma unroll
            for (int i = 0; i < 8; ++i) {
                const int u = tid + i * 256;
                const int r = u >> 4, c8 = (u & 15) * 8;
                *(uint4*)(C + (size_t)(row0 + r) * QKP_ + col0 + c8) =
                    *(const uint4*)(pkB + ((r * 256 + c8 * 2) ^ ((r & 7) << 4)));
            }
        } else {
            // pack transposed [dl 128][tl 128], swz ^((dl&7)<<4); 8B uint2 per
            // (m,n,lane) covers tl0..tl0+3 (tl0 % 4 == 0 -> 8B aligned)
            #pragma unroll
            for (int m = 0; m < 4; ++m) {
                #pragma unroll
                for (int n = 0; n < 4; ++n) {
                    const int tl0 = wr * 64 + m * 16 + lhi * 4;
                    const int dl = wc * 64 + n * 16 + lane15;
                    const int off = (dl * 256 + tl0 * 2) ^ ((dl & 7) << 4);
                    *(uint2*)(pkB + off) = make_uint2(
                        pack2(acc[m][n][0], acc[m][n][1]),
                        pack2(acc[m][n][2], acc[m][n][3]));
                }
            }
            __syncthreads();
            const int h0  = (col0 - 512) >> 6;   // first of the 2 heads in this tile
            const int bb  = row0 >> 11;
            const int t0l = row0 & 2047;
            #pragma unroll
            for (int i = 0; i < 8; ++i) {
                const int u = tid + i * 256;
                const int d = u >> 4, t8 = (u & 15) * 8;
                const int hg = h0 + (d >> 6), dd = d & 63;
                const int off = (d * 256 + t8 * 2) ^ ((d & 7) << 4);
                *(uint4*)(vTout + ((size_t)((bb * 16 + hg) * 64 + dd)) * 2048 + t0l + t8) =
                    *(const uint4*)(pkB + off);
            }
        }
    }
}

// ---------------------------------------------------------------------------
// Chunk-local sums, 512 threads (MFMA kv): per (b,h,chunk):
//   waves 0-3: kv_loc[d][c] = sum_t v[t,d]*ke[t,c]  via 16 MFMAs (keT transpose)
//   waves 4-7: ke_loc[c]    = sum_t ke[t,c]
__global__ __launch_bounds__(512)
void prep_attn_kernel(const ushort* __restrict__ qkcv, const ushort* __restrict__ vT,
                      float* __restrict__ ke_loc, float* __restrict__ kv_loc) {
    const int bid = blockIdx.x;            // bh*NC_ + chunk
    const int chunk = bid & (NC_ - 1);
    const int bh = bid >> 4;
    const int b = bh >> 4, h = bh & 15;
    const int t0 = chunk * L_;
    const int tid = threadIdx.x;
    const int wave = tid >> 6, lane = tid & 63;
    const int l15 = lane & 15, lhi = lane >> 4;

    __shared__ __align__(16) ushort ke_bf[128 * 32];   // 8 KB, swz ((t>>1)&3)<<4
    __shared__ __align__(16) ushort keTs[16 * 128];    // 4 KB, [c][t] swz ^(c<<4)
    __shared__ __align__(16) ushort Vt_s[64 * 128];    // 16 KB, [d][s] swz (d&15)<<4
    __shared__ float gsum[16][16];
    char* keB = (char*)ke_bf;
    char* keT = (char*)keTs;
    char* vtB = (char*)Vt_s;

    // ---- stage ke = exp(kc) bf16 (swizzled + transposed copies) ----
    if (tid < 256) {
        const int t = tid >> 1, c0 = (tid & 1) * 8;
        uint4 raw = *(const uint4*)(qkcv + (size_t)(b * T_ + t0 + t) * QKP_ + 256 + h * C_ + c0);
        float f[8]; unpack8(raw, f);
        float ef[8];
        #pragma unroll
        for (int j = 0; j < 8; ++j) ef[j] = __expf(f[j]);
        uint4 o;
        o.x = pack2(ef[0], ef[1]); o.y = pack2(ef[2], ef[3]);
        o.z = pack2(ef[4], ef[5]); o.w = pack2(ef[6], ef[7]);
        const int swz = ((t >> 1) & 3) << 4;
        *(uint4*)(keB + ((t * 64 + c0 * 2) ^ swz)) = o;
        *(uint4*)(keB + ((t * 64 + 32 + c0 * 2) ^ swz)) = make_uint4(0, 0, 0, 0);
        #pragma unroll
        for (int j = 0; j < 8; ++j) {
            const int c = c0 + j;
            *(ushort*)(keT + (((c << 8) + (t << 1)) ^ (c << 4))) = f2b(ef[j]);
        }
    }
    // ---- stage Vt (bf16 [d][s] swizzled) from vT global, all 512 threads ----
    {
        const int d = tid >> 3, qq = tid & 7;
        const ushort* src = vT + ((size_t)bh * 64 + d) * 2048 + t0 + qq * 16;
        const int swz = (d & 15) << 4;
        #pragma unroll
        for (int ii = 0; ii < 2; ++ii) {
            uint4 raw = *(const uint4*)(src + ii * 8);
            *(uint4*)(vtB + ((d * 256 + qq * 32 + ii * 16) ^ swz)) = raw;
        }
    }
    __syncthreads();

    // ---- waves 0-3: kv^T[d][c] via MFMA; waves 4-7: ke column partial sums ----
    if (wave < 4) {
        const int dt = wave;
        f32x4 kacc = (f32x4){0.f, 0.f, 0.f, 0.f};
        #pragma unroll
        for (int ks = 0; ks < 4; ++ks) {
            const int d = dt * 16 + l15;
            short8 av = *(const short8*)(vtB + ((d * 256 + ks * 64 + lhi * 16) ^ ((d & 15) << 4)));
            short8 bk = *(const short8*)(keT + (((l15 << 8) + ks * 64 + lhi * 16) ^ (l15 << 4)));
            kacc = __builtin_amdgcn_mfma_f32_16x16x32_bf16(av, bk, kacc, 0, 0, 0);
        }
        float* kvb = kv_loc + (size_t)bid * 1024;
        #pragma unroll
        for (int j = 0; j < 4; ++j)
            kvb[(dt * 16 + lhi * 4 + j) * 16 + l15] = kacc[j];
    } else {
        const int cc = tid & 15, g = (tid >> 4) & 15;
        float s = 0.f;
        #pragma unroll
        for (int u = 0; u < 8; ++u) {
            const int t = g * 8 + u;
            s += b2f(*(const ushort*)(keB + ((t * 64 + cc * 2) ^ (((t >> 1) & 3) << 4))));
        }
        gsum[cc][g] = s;
    }
    __syncthreads();
    if (tid < 16) {
        float s = 0.f;
        #pragma unroll
        for (int g = 0; g < 16; ++g) s += gsum[tid][g];
        ke_loc[(size_t)bid * C_ + tid] = s;
    }
}

// ---------------------------------------------------------------------------
// MFMA intra, 8 waves (512 threads): per (b,h,chunk):
//   exclusive chunk-prefix of ke_loc/kv_loc computed in-kernel (sum ch<chunk)
//   P^T = Ke·Qn^T (one s-block per wave), causal mask, P -> swizzled LDS bf16
//   O = Qn·S0 + P·V; output packed via Pl -> vectorized stores.
__global__ __launch_bounds__(512)
void intra_kernel(const ushort* __restrict__ qkcv, const ushort* __restrict__ vT,
                  const float* __restrict__ ke_loc, const float* __restrict__ kv_loc,
                  ushort* __restrict__ xob) {
    const int bid = blockIdx.x;
    const int chunk = bid & (NC_ - 1);
    const int bh = bid >> 4;
    const int b = bh >> 4, h = bh & 15;
    const int t0 = chunk * L_;
    const int tid = threadIdx.x;
    const int wave = tid >> 6, lane = tid & 63;
    const int l15 = lane & 15, lhi = lane >> 4;

    __shared__ __align__(16) ushort ke_bf[128 * 32];
    __shared__ __align__(16) ushort qn_bf[128 * 32];
    __shared__ __align__(16) ushort Vt_s[64 * 128];
    __shared__ __align__(16) ushort Pl[128 * 128];
    __shared__ __align__(16) ushort S0t[64 * 32];
    __shared__ float kesum_s[128][16];
    __shared__ float gsum[16][16];
    __shared__ float e0s[16];

    char* keB = (char*)ke_bf;
    char* qnB = (char*)qn_bf;
    char* vtB = (char*)Vt_s;
    char* plB = (char*)Pl;
    char* s0B = (char*)S0t;

    // ---- region 1: stage ke (waves 0-3), Vt (all), e0 (tid<16) ----
    if (tid < 256) {
        const int t = tid >> 1, c0 = (tid & 1) * 8;
        uint4 raw = *(const uint4*)(qkcv + (size_t)(b * T_ + t0 + t) * QKP_ + 256 + h * C_ + c0);
        float f[8]; unpack8(raw, f);
        uint4 o;
        o.x = pack2(__expf(f[0]), __expf(f[1]));
        o.y = pack2(__expf(f[2]), __expf(f[3]));
        o.z = pack2(__expf(f[4]), __expf(f[5]));
        o.w = pack2(__expf(f[6]), __expf(f[7]));
        const int swz = ((t >> 1) & 3) << 4;
        *(uint4*)(keB + ((t * 64 + c0 * 2) ^ swz)) = o;
        *(uint4*)(keB + ((t * 64 + 32 + c0 * 2) ^ swz)) = make_uint4(0, 0, 0, 0);
    }
    {
        const int d = tid >> 3, qq = tid & 7;
        const ushort* src = vT + ((size_t)bh * 64 + d) * 2048 + t0 + qq * 16;
        const int swz = (d & 15) << 4;
        #pragma unroll
        for (int ii = 0; ii < 2; ++ii) {
            uint4 raw = *(const uint4*)(src + ii * 8);
            *(uint4*)(vtB + ((d * 256 + qq * 32 + ii * 16) ^ swz)) = raw;
        }
    }
    if (tid < 16) {
        float s = 0.f;
        for (int ch = 0; ch < chunk; ++ch)
            s += ke_loc[(size_t)(bh * NC_ + ch) * C_ + tid];
        e0s[tid] = s;
    }
    __syncthreads();

    // ---- region 2 (parallel): waves 0-3 S0-prefix; waves 4-7 gsum partials ----
    if (tid < 256) {
        const int d = tid >> 2;
        const int c0 = (tid & 3) * 4;
        const float* base = kv_loc + (size_t)(bh * NC_) * 1024 + d * 16 + c0;
        float s0 = 0.f, s1 = 0.f, s2 = 0.f, s3 = 0.f;
        for (int ch = 0; ch < chunk; ++ch) {
            float4 t4 = *(const float4*)(base + ch * 1024);
            s0 += t4.x; s1 += t4.y; s2 += t4.z; s3 += t4.w;
        }
        const int swz2 = ((d >> 1) & 3) << 4;
        *(uint2*)(s0B + ((d * 64 + c0 * 2) ^ swz2)) =
            make_uint2(pack2(s0, s1), pack2(s2, s3));
        // zero-pad cols 16..31 (bytes 32..63)
        *(uint2*)(s0B + ((d * 64 + 32 + (tid & 3) * 8) ^ swz2)) = make_uint2(0, 0);
    } else {
        const int cc = tid & 15, g = (tid >> 4) & 15;
        float s = 0.f;
        #pragma unroll
        for (int u = 0; u < 8; ++u) {
            const int t = g * 8 + u;
            s += b2f(*(const ushort*)(keB + ((t * 64 + cc * 2) ^ (((t >> 1) & 3) << 4))));
        }
        gsum[cc][g] = s;
    }
    __syncthreads();
    if (tid < 16) {
        float run = e0s[tid];
        #pragma unroll
        for (int g = 0; g < 16; ++g) { float tmp = gsum[tid][g]; gsum[tid][g] = run; run += tmp; }
    }
    __syncthreads();
    if (tid < 256) {
        const int cc = tid & 15, g = tid >> 4;
        float run = gsum[cc][g];
        #pragma unroll
        for (int u = 0; u < 8; ++u) {
            const int t = g * 8 + u;
            run += b2f(*(const ushort*)(keB + ((t * 64 + cc * 2) ^ (((t >> 1) & 3) << 4))));
            kesum_s[t][cc] = run;
        }
    }
    __syncthreads();

    // ---- qn = softmax(qc)*scale/(kesum+eps), bf16 (+ zero pad) ----
    if (tid < 128) {
        const int t = tid;
        const ushort* qrow = qkcv + (size_t)(b * T_ + t0 + t) * QKP_ + h * C_;
        float qv[16];
        uint4 r0 = *(const uint4*)qrow, r1 = *(const uint4*)(qrow + 8);
        unpack8(r0, qv); unpack8(r1, qv + 8);
        float m = qv[0];
        #pragma unroll
        for (int c = 1; c < 16; ++c) m = fmaxf(m, qv[c]);
        float sum = 0.f;
        #pragma unroll
        for (int c = 0; c < 16; ++c) { qv[c] = __expf(qv[c] - m); sum += qv[c]; }
        const float inv = SCALE_ / sum;
        #pragma unroll
        for (int c = 0; c < 16; ++c) qv[c] = qv[c] * inv / (kesum_s[t][c] + 1e-9f);
        uint4 o0, o1;
        o0.x = pack2(qv[0], qv[1]);   o0.y = pack2(qv[2], qv[3]);
        o0.z = pack2(qv[4], qv[5]);   o0.w = pack2(qv[6], qv[7]);
        o1.x = pack2(qv[8], qv[9]);   o1.y = pack2(qv[10], qv[11]);
        o1.z = pack2(qv[12], qv[13]); o1.w = pack2(qv[14], qv[15]);
        const int swz = ((t >> 1) & 3) << 4;
        *(uint4*)(qnB + ((t * 64) ^ swz)) = o0;
        *(uint4*)(qnB + ((t * 64 + 16) ^ swz)) = o1;
        *(uint4*)(qnB + ((t * 64 + 32) ^ swz)) = make_uint4(0, 0, 0, 0);
        *(uint4*)(qnB + ((t * 64 + 48) ^ swz)) = make_uint4(0, 0, 0, 0);
    }
    __syncthreads();

    // ---- QK: one s-block per wave: P^T = Ke·Qn^T, mask, write Pl ----
    {
        const int sb = wave;               // 0..7
        const int s_row = sb * 16 + l15;
        short8 af = *(const short8*)(keB + ((s_row * 64 + lhi * 16) ^ (((s_row >> 1) & 3) << 4)));
        #pragma unroll
        for (int tb = 0; tb < 8; ++tb) {
            f32x4 p = (f32x4){0.f, 0.f, 0.f, 0.f};
            if (tb >= sb) {
                const int t_col = tb * 16 + l15;
                short8 bf = *(const short8*)(qnB + ((t_col * 64 + lhi * 16) ^ (((t_col >> 1) & 3) << 4)));
                p = __builtin_amdgcn_mfma_f32_16x16x32_bf16(af, bf, p, 0, 0, 0);
                if (tb == sb) {
                    #pragma unroll
                    for (int j = 0; j < 4; ++j)
                        p[j] = (lhi * 4 + j > l15) ? 0.f : p[j];
                }
            }
            const int t_g = tb * 16 + l15;
            const int sbase = sb * 16 + lhi * 4;
            const int swz = (t_g & 15) << 4;
            *(uint32_t*)(plB + ((t_g * 256 + sbase * 2) ^ swz)) = pack2(p[0], p[1]);
            *(uint32_t*)(plB + ((t_g * 256 + sbase * 2 + 4) ^ swz)) = pack2(p[2], p[3]);
        }
    }
    __syncthreads();

    // ---- O = Qn·S0 + P·V : one t-tile per wave ----
    f32x4 acc4[4];
    #pragma unroll
    for (int dt = 0; dt < 4; ++dt) acc4[dt] = (f32x4){0.f, 0.f, 0.f, 0.f};

    {
        const int t_g = wave * 16 + l15;
        short8 aq = *(const short8*)(qnB + ((t_g * 64 + lhi * 16) ^ (((t_g >> 1) & 3) << 4)));
        #pragma unroll
        for (int dt = 0; dt < 4; ++dt) {
            const int d = dt * 16 + l15;
            short8 bs = *(const short8*)(s0B + ((d * 64 + lhi * 16) ^ (((d >> 1) & 3) << 4)));
            acc4[dt] = __builtin_amdgcn_mfma_f32_16x16x32_bf16(aq, bs, acc4[dt], 0, 0, 0);
        }
        const int pswz = (t_g & 15) << 4;
        #pragma unroll
        for (int kb = 0; kb < 4; ++kb) {
            short8 ap = *(const short8*)(plB + ((t_g * 256 + kb * 64 + lhi * 16) ^ pswz));
            #pragma unroll
            for (int dt = 0; dt < 4; ++dt) {
                const int d = dt * 16 + l15;
                short8 bv = *(const short8*)(vtB + ((d * 256 + kb * 64 + lhi * 16) ^ ((d & 15) << 4)));
                acc4[dt] = __builtin_amdgcn_mfma_f32_16x16x32_bf16(ap, bv, acc4[dt], 0, 0, 0);
            }
        }
    }

    // ---- epilogue: pack O into dead Pl as [t][d], then vectorized stores ----
    __syncthreads();   // all PV reads of Pl done
    {
        ushort* ob = (ushort*)Pl;
        const int tl = wave * 16 + lhi * 4;
        #pragma unroll
        for (int dt = 0; dt < 4; ++dt) {
            const int d = dt * 16 + l15;
            #pragma unroll
            for (int j = 0; j < 4; ++j)
                ob[(tl + j) * 64 + d] = f2b(acc4[dt][j]);
        }
    }
    __syncthreads();
    {
        const ushort* ob = (const ushort*)Pl;
        #pragma unroll
        for (int i = 0; i < 2; ++i) {
            const int u = tid + i * 512;
            const int t = u >> 3, c8 = (u & 7) * 8;
            *(uint4*)(xob + (size_t)(b * T_ + t0 + t) * D_ + h * HD_ + c8) =
                *(const uint4*)(ob + t * 64 + c8);
        }
    }
}

// ---------------------------------------------------------------------------
extern "C" void kernel_launch(void* const* d_in, const int* in_sizes, int n_in,
                              void* d_out, int out_size, void* d_ws, size_t ws_size,
                              hipStream_t stream) {
    const float* x     = (const float*)d_in[0];   // (2,2048,1024)
    const float* w_qkv = (const float*)d_in[1];   // (3072,1024)
    const float* w_out = (const float*)d_in[2];   // (1024,1024)
    const float* code  = (const float*)d_in[3];   // (1,16,16,64)
    float* out = (float*)d_out;                   // (2,2048,1024)

    ushort* xb    = (ushort*)d_ws;                    // 4096*1024
    ushort* WallB = xb + (size_t)4096 * 1024;         // 1536*1024
    ushort* WoB   = WallB + (size_t)1536 * 1024;      // 1024*1024
    ushort* qkcv  = WoB + (size_t)1024 * 1024;        // 4096*512 (qc|kc)
    ushort* xob   = qkcv + (size_t)4096 * 512;        // 4096*1024
    ushort* vT    = xob + (size_t)4096 * 1024;        // 32*64*2048
    float*  ke_loc = (float*)(vT + (size_t)32 * 64 * 2048);  // 512*16
    float*  kv_loc = ke_loc + 512 * 16;               // 512*1024 ([d][c] per chunk)

    // merged casts + weight folding (one launch)
    prep_inputs_kernel<<<3200, 256, 0, stream>>>(x, w_qkv, w_out, code, xb, WallB, WoB);

    // fused qc|kc|v projection: (4096 x 1536 x 1024); qc/kc -> qkcv, v -> vT (transposed)
    gemm_bf16_kernel<2><<<dim3(12, 32), 256, 0, stream>>>(xb, WallB, qkcv, vT, 4096, 1536, 1024);

    // chunk-local sums via MFMA (locals only; prefix in intra)
    prep_attn_kernel<<<512, 512, 0, stream>>>(qkcv, vT, ke_loc, kv_loc);
    intra_kernel<<<512, 512, 0, stream>>>(qkcv, vT, ke_loc, kv_loc, xob);

    // out = xo @ w_out^T  (4096 x 1024 x 1024), fp32 out
    gemm_bf16_kernel<0><<<dim3(8, 32), 256, 0, stream>>>(xob, WoB, out, nullptr, 4096, 1024, 1024);
}